// Round 8
// baseline (541.456 us; speedup 1.0000x reference)
//
#include <hip/hip_runtime.h>
#include <hip/hip_bf16.h>
#include <cstdint>
#include <cstddef>

typedef __hip_bfloat16 bf16;
typedef float f4 __attribute__((ext_vector_type(4)));
typedef float f32x4 __attribute__((ext_vector_type(4)));
typedef short s8v __attribute__((ext_vector_type(8)));
typedef unsigned short u16x4 __attribute__((ext_vector_type(4)));

#define LN_EPS 1e-5f
#define LOG2E 1.4426950408889634f

// async global->LDS 16B per lane: lds dest = base + lane*16 (wave-uniform base)
__device__ __forceinline__ void async_cp16(const void* g, void* lds) {
  __builtin_amdgcn_global_load_lds(
      (const __attribute__((address_space(1))) unsigned int*)g,
      (__attribute__((address_space(3))) unsigned int*)lds, 16, 0, 0);
}

__device__ __forceinline__ uint32_t pkbf(float lo, float hi) {
  bf16 a = __float2bfloat16(lo), c = __float2bfloat16(hi);
  return (uint32_t)*(unsigned short*)&a | ((uint32_t)*(unsigned short*)&c << 16);
}

// ------------------------------------------------------------------
// fused multi-segment cast fp32 -> bf16
// ------------------------------------------------------------------
#define NCAST 16
struct CastArgs {
  const float* in[NCAST];
  bf16* out[NCAST];
  int end4[NCAST];
  int nseg;
};

__global__ __launch_bounds__(256) void cast_multi(CastArgs a, int total4) {
  int i = blockIdx.x * 256 + threadIdx.x;
  if (i >= total4) return;
  int s = 0;
  while (i >= a.end4[s]) ++s;
  int j = i - (s ? a.end4[s - 1] : 0);
  f4 v = ((const f4*)a.in[s])[j];
  u16x4 o;
#pragma unroll
  for (int c = 0; c < 4; ++c) {
    bf16 h = __float2bfloat16(v[c]);
    o[c] = *reinterpret_cast<unsigned short*>(&h);
  }
  ((u16x4*)a.out[s])[j] = o;
}

// scale fp32 array by constant (cam_mask * log2e)
__global__ __launch_bounds__(256) void scale_f32_kernel(const float* __restrict__ in,
                                                        float* __restrict__ out,
                                                        float s, int n4) {
  int i = blockIdx.x * 256 + threadIdx.x;
  if (i < n4) {
    f4 v = ((const f4*)in)[i];
    ((f4*)out)[i] = v * s;
  }
}

// ------------------------------------------------------------------
// add fp32 + fp32 -> bf16
// ------------------------------------------------------------------
__global__ __launch_bounds__(256) void add_bf16_kernel(const float* __restrict__ a,
                                                       const float* __restrict__ b,
                                                       bf16* __restrict__ out, int n4) {
  int i = blockIdx.x * 256 + threadIdx.x;
  if (i < n4) {
    f4 x = ((const f4*)a)[i];
    f4 y = ((const f4*)b)[i];
    u16x4 o;
#pragma unroll
    for (int j = 0; j < 4; ++j) {
      bf16 h = __float2bfloat16(x[j] + y[j]);
      o[j] = *reinterpret_cast<unsigned short*>(&h);
    }
    ((u16x4*)out)[i] = o;
  }
}

// ------------------------------------------------------------------
// MFMA GEMM: C[M,N] = A[M,K] @ W[N,K]^T (+ bias[N])
// global_load_lds staging, linear LDS [TB][64] bf16, XOR-swizzled source
// columns + swizzled ds_read (involution: slot ^= row&7).
// MODE: 0 f32, 2 bf16+relu, 3 bf16 head layout (sec0 scaled by qscale),
//       4 f32 split-K partial, 5 bf16 transposed head layout (V^T, per-sec)
// ------------------------------------------------------------------
template <int TB, int MODE, int SPLITK>
__global__ __launch_bounds__(256, 2) void mfma_gemm(
    const bf16* __restrict__ A, const bf16* __restrict__ W,
    const float* __restrict__ bias, float* __restrict__ C,
    bf16* __restrict__ Cb, int M, int N, int K, int HL, float qscale) {
  constexpr int WM = TB / 2, WN = TB / 2;
  constexpr int MR = WM / 16, NR = WN / 16;
  constexpr int NCH = TB / 32;
  __shared__ __attribute__((aligned(16))) unsigned short As[TB][64];
  __shared__ __attribute__((aligned(16))) unsigned short Ws[TB][64];
  const int tid = threadIdx.x;
  const int lane = tid & 63, wave = tid >> 6;
  const int wr = wave >> 1, wc = wave & 1;
  const int bm = blockIdx.x * TB, bn = blockIdx.y * TB;
  const int fr = lane & 15, fo = lane >> 4;
  const int srowi = lane >> 3;
  const int slot = lane & 7;
  const int gcol = (slot ^ srowi) * 8;

  const int kchunk = K / SPLITK;
  const int kbeg = (SPLITK > 1) ? blockIdx.z * kchunk : 0;

  f32x4 acc[MR][NR] = {};

  for (int k0 = kbeg; k0 < kbeg + kchunk; k0 += 64) {
    __syncthreads();
#pragma unroll
    for (int c = 0; c < NCH; ++c) {
      int rbase = wave * (TB / 4) + c * 8;
      int row = rbase + srowi;
      async_cp16(A + (size_t)(bm + row) * K + k0 + gcol, &As[rbase][0]);
      async_cp16(W + (size_t)(bn + row) * K + k0 + gcol, &Ws[rbase][0]);
    }
    __syncthreads();
#pragma unroll
    for (int ks = 0; ks < 2; ++ks) {
      s8v a[MR], b[NR];
#pragma unroll
      for (int mi = 0; mi < MR; ++mi) {
        int row = wr * WM + mi * 16 + fr;
        a[mi] = *(const s8v*)((const char*)&As[0][0] + row * 128 +
                              ((ks * 64 + fo * 16) ^ ((row & 7) << 4)));
      }
#pragma unroll
      for (int ni = 0; ni < NR; ++ni) {
        int row = wc * WN + ni * 16 + fr;
        b[ni] = *(const s8v*)((const char*)&Ws[0][0] + row * 128 +
                              ((ks * 64 + fo * 16) ^ ((row & 7) << 4)));
      }
#pragma unroll
      for (int mi = 0; mi < MR; ++mi)
#pragma unroll
        for (int ni = 0; ni < NR; ++ni)
          acc[mi][ni] = __builtin_amdgcn_mfma_f32_16x16x32_bf16(
              a[mi], b[ni], acc[mi][ni], 0, 0, 0);
    }
  }

  const int r0 = (lane >> 4) * 4;
  float* Cz = (MODE == 4) ? C + (size_t)blockIdx.z * M * N : C;
#pragma unroll
  for (int mi = 0; mi < MR; ++mi) {
#pragma unroll
    for (int ni = 0; ni < NR; ++ni) {
      int col = bn + wc * WN + ni * 16 + fr;
      float bv = (MODE == 4) ? 0.f : bias[col];
#pragma unroll
      for (int r = 0; r < 4; ++r) {
        int row = bm + wr * WM + mi * 16 + r0 + r;
        float t = acc[mi][ni][r] + bv;
        if (MODE == 2) t = fmaxf(t, 0.f);
        if (MODE == 0) {
          C[(size_t)row * N + col] = t;
        } else if (MODE == 4) {
          Cz[(size_t)row * N + col] = t;
        } else if (MODE == 3) {
          int l = row >> 3, bb = row & 7;
          int sec = col >> 8, hh = (col >> 5) & 7, d = col & 31;
          if (sec == 0) t *= qscale;
          Cb[(size_t)sec * ((size_t)64 * HL * 32) +
             ((size_t)(bb * 8 + hh) * HL + l) * 32 + d] = __float2bfloat16(t);
        } else if (MODE == 5) {
          int l = row >> 3, bb = row & 7;
          int sec = col >> 8, hh = (col >> 5) & 7, d = col & 31;
          Cb[(size_t)sec * ((size_t)64 * 32 * HL) +
             ((size_t)(bb * 8 + hh) * 32 + d) * HL + l] = __float2bfloat16(t);
        } else {
          Cb[(size_t)row * N + col] = __float2bfloat16(t);
        }
      }
    }
  }
}

// ------------------------------------------------------------------
// Swapped-operand MFMA flash attention (in-lane softmax, no barriers).
// Qh: (64, L, 32) bf16, pre-scaled by (1/sqrt(32))*log2e.
// Kh: (64, S, 32) bf16. VhT: (64, 32, S) bf16 (transposed head layout).
// bias (optional): (8, L, S) fp32, pre-scaled by log2e.
// NW waves/block, 16 q-rows per wave.
// grid (64 bh, ceil(L/(NW*16)), nz). block NW*64.
// ------------------------------------------------------------------
template <int HAS_BIAS, int PARTIAL, int NW>
__global__ __launch_bounds__(NW * 64, 8) void attn_mfma(
    const bf16* __restrict__ Qh, const bf16* __restrict__ Kh,
    const bf16* __restrict__ VhT, const float* __restrict__ bias,
    bf16* __restrict__ O, float* __restrict__ PO, float* __restrict__ PM,
    float* __restrict__ PL, int L, int S, int SC) {
  __shared__ __attribute__((aligned(16))) uint32_t Ps2[NW][16][36];
  const int tid = threadIdx.x;
  const int lane = tid & 63, wave = tid >> 6;
  const int fr = lane & 15, fo = lane >> 4;
  const int bh = blockIdx.x;
  const int b = bh >> 3, h = bh & 7;
  const int q0 = blockIdx.y * (NW * 16) + wave * 16;
  const int q = q0 + fr;

  const int cz = PARTIAL ? blockIdx.z : 0;
  const int sb = PARTIAL ? cz * SC : 0;
  const int se = PARTIAL ? min(S, sb + SC) : S;

  s8v qf = {};
  if (q < L) qf = *(const s8v*)(Qh + ((size_t)bh * L + q) * 32 + fo * 8);

  const float* brow = nullptr;
  if (HAS_BIAS) brow = bias + ((size_t)b * L + (q < L ? q : L - 1)) * S;

  float m = -1e30f, lsum = 0.f;
  f32x4 oacc[2] = {};

  // K fragment loader: kf[kb] = K[key = s0 + kb*16 + fr][d = fo*8..+7]
  s8v kf[4];
#pragma unroll
  for (int kb = 0; kb < 4; ++kb)
    kf[kb] = *(const s8v*)(Kh + ((size_t)bh * S + sb + kb * 16 + fr) * 32 + fo * 8);

  for (int s0 = sb; s0 < se; s0 += 64) {
    const bool more = (s0 + 64 < se);
    s8v kn[4];
    if (more) {
#pragma unroll
      for (int kb = 0; kb < 4; ++kb)
        kn[kb] = *(const s8v*)(Kh + ((size_t)bh * S + s0 + 64 + kb * 16 + fr) * 32 + fo * 8);
    }
    // V^T fragments: vf[dh][ks] = V^T[d = dh*16 + fr][key = s0 + ks*32 + fo*8..+7]
    s8v vf[2][2];
#pragma unroll
    for (int dh = 0; dh < 2; ++dh)
#pragma unroll
      for (int ks = 0; ks < 2; ++ks)
        vf[dh][ks] = *(const s8v*)(VhT + ((size_t)bh * 32 + dh * 16 + fr) * S +
                                   s0 + ks * 32 + fo * 8);
    f4 bias4[4];
    if (HAS_BIAS) {
#pragma unroll
      for (int kb = 0; kb < 4; ++kb)
        bias4[kb] = *(const f4*)(brow + s0 + kb * 16 + 4 * fo);
    }

    // QK^T swapped: sa[kb] = S^T[key-block][q]; col=q=fr, row=4*fo+r
    f32x4 sa[4];
#pragma unroll
    for (int kb = 0; kb < 4; ++kb) {
      f32x4 z = {};
      sa[kb] = __builtin_amdgcn_mfma_f32_16x16x32_bf16(kf[kb], qf, z, 0, 0, 0);
    }

    float lg[16];
#pragma unroll
    for (int kb = 0; kb < 4; ++kb)
#pragma unroll
      for (int r = 0; r < 4; ++r)
        lg[kb * 4 + r] = HAS_BIAS ? sa[kb][r] + bias4[kb][r] : sa[kb][r];

    if (s0 + 64 > se) {  // boundary tile: mask invalid keys
#pragma unroll
      for (int kb = 0; kb < 4; ++kb)
#pragma unroll
        for (int r = 0; r < 4; ++r)
          if (s0 + kb * 16 + 4 * fo + r >= se) lg[kb * 4 + r] = -1e30f;
    }

    // tile max: in-lane chain + 2 cross-fo shuffles
    float tm = lg[0];
#pragma unroll
    for (int i = 1; i < 16; ++i) tm = fmaxf(tm, lg[i]);
    tm = fmaxf(tm, __shfl_xor(tm, 16));
    tm = fmaxf(tm, __shfl_xor(tm, 32));

    // deferred rescale (wave-uniform)
    if (__any(tm > m + 8.f)) {
      float nm = fmaxf(m, tm);
      float rs = exp2f(m - nm);
      m = nm;
      lsum *= rs;
#pragma unroll
      for (int r = 0; r < 4; ++r) { oacc[0][r] *= rs; oacc[1][r] *= rs; }
    }

    float pr[16];
    float ps = 0.f;
#pragma unroll
    for (int i = 0; i < 16; ++i) {
      pr[i] = exp2f(lg[i] - m);
      ps += pr[i];
    }
    lsum += ps;  // partial (this lane's 16 keys); cross-fo reduced at end

    // pack P -> per-wave LDS: row=q(fr), u32 idx = key/2
#pragma unroll
    for (int kb = 0; kb < 4; ++kb) {
      uint32_t w0 = pkbf(pr[kb * 4 + 0], pr[kb * 4 + 1]);
      uint32_t w1 = pkbf(pr[kb * 4 + 2], pr[kb * 4 + 3]);
      uint64_t w = (uint64_t)w0 | ((uint64_t)w1 << 32);
      *(uint64_t*)&Ps2[wave][fr][kb * 8 + 2 * fo] = w;
    }

    // P^T fragments: pf[ks] lane holds P[q=fr][key = ks*32 + fo*8..+7]
    s8v pf[2];
#pragma unroll
    for (int ks = 0; ks < 2; ++ks)
      pf[ks] = *(const s8v*)&Ps2[wave][fr][ks * 16 + 4 * fo];

    // PV swapped: oacc[dh] = O^T[d][q], col=q=fr, row d = dh*16 + 4*fo + r
#pragma unroll
    for (int dh = 0; dh < 2; ++dh)
#pragma unroll
      for (int ks = 0; ks < 2; ++ks)
        oacc[dh] = __builtin_amdgcn_mfma_f32_16x16x32_bf16(
            vf[dh][ks], pf[ks], oacc[dh], 0, 0, 0);

    if (more) {
#pragma unroll
      for (int kb = 0; kb < 4; ++kb) kf[kb] = kn[kb];
    }
  }

  // full row-sum across the 4 fo-lanes
  lsum += __shfl_xor(lsum, 16);
  lsum += __shfl_xor(lsum, 32);

  if (q < L) {
    if (PARTIAL) {
      size_t pi = ((size_t)cz * 64 + bh) * L + q;
      float* po = PO + pi * 32;
#pragma unroll
      for (int dh = 0; dh < 2; ++dh) {
        f4 t;
#pragma unroll
        for (int r = 0; r < 4; ++r) t[r] = oacc[dh][r];
        *(f4*)(po + dh * 16 + 4 * fo) = t;
      }
      if (fo == 0) { PM[pi] = m; PL[pi] = lsum; }
    } else {
      float inv = 1.f / lsum;
      bf16* op = O + ((size_t)q * 8 + b) * 256 + h * 32;
#pragma unroll
      for (int dh = 0; dh < 2; ++dh) {
        uint32_t w0 = pkbf(oacc[dh][0] * inv, oacc[dh][1] * inv);
        uint32_t w1 = pkbf(oacc[dh][2] * inv, oacc[dh][3] * inv);
        *(uint32_t*)(op + dh * 16 + 4 * fo) = w0;
        *(uint32_t*)(op + dh * 16 + 4 * fo + 2) = w1;
      }
    }
  }
}

// ------------------------------------------------------------------
// combine NC S-chunk partials -> O bf16 (thread per (bh,q,d))
// NOTE: PM/PL are in log2 domain (exp2 weights).
// ------------------------------------------------------------------
__global__ __launch_bounds__(256) void attn_combine(
    const float* __restrict__ PO, const float* __restrict__ PM,
    const float* __restrict__ PL, bf16* __restrict__ O, int L, int NC) {
  int gid = blockIdx.x * 256 + threadIdx.x;
  if (gid >= 64 * L * 32) return;
  int d = gid & 31;
  int rem = gid >> 5;
  int q = rem % L, bh = rem / L;
  int b = bh >> 3, h = bh & 7;
  float M = -1e30f;
  for (int c = 0; c < NC; ++c) M = fmaxf(M, PM[((size_t)c * 64 + bh) * L + q]);
  float lsum = 0.f, o = 0.f;
  for (int c = 0; c < NC; ++c) {
    size_t pi = ((size_t)c * 64 + bh) * L + q;
    float w = exp2f(PM[pi] - M);
    lsum += PL[pi] * w;
    o += PO[pi * 32 + d] * w;
  }
  O[((size_t)q * 8 + b) * 256 + h * 32 + d] = __float2bfloat16(o / lsum);
}

// ------------------------------------------------------------------
// LayerNorm over last dim (256): v = x (+res) (+Σ parts) (+gbias);
// out = LN(v)*g + b ; dual output (f32 + bf16)
// ------------------------------------------------------------------
__global__ __launch_bounds__(256) void ln_kernel(
    const float* __restrict__ x, const float* __restrict__ res,
    const float* __restrict__ parts, int nparts, int pstride,
    const float* __restrict__ gbias,
    const float* __restrict__ g, const float* __restrict__ b,
    float* __restrict__ out, bf16* __restrict__ outb) {
  const int row = blockIdx.x, tid = threadIdx.x;
  size_t idx = (size_t)row * 256 + tid;
  float v = x[idx];
  if (res) v += res[idx];
  if (parts) {
    for (int z = 0; z < nparts; ++z) v += parts[(size_t)z * pstride + idx];
  }
  if (gbias) v += gbias[tid];
  float s = v, s2 = v * v;
#pragma unroll
  for (int off = 32; off >= 1; off >>= 1) {
    s += __shfl_down(s, off);
    s2 += __shfl_down(s2, off);
  }
  __shared__ float red[8];
  int wv = tid >> 6;
  if ((tid & 63) == 0) { red[wv] = s; red[4 + wv] = s2; }
  __syncthreads();
  if (tid == 0) {
    float ts = red[0] + red[1] + red[2] + red[3];
    float ts2 = red[4] + red[5] + red[6] + red[7];
    float mu = ts * (1.f / 256.f);
    float var = ts2 * (1.f / 256.f) - mu * mu;
    red[0] = mu;
    red[1] = rsqrtf(var + LN_EPS);
  }
  __syncthreads();
  float y = (v - red[0]) * red[1] * g[tid] + b[tid];
  if (out) out[idx] = y;
  if (outb) outb[idx] = __float2bfloat16(y);
}

// ------------------------------------------------------------------
// Host orchestration
// ------------------------------------------------------------------
extern "C" void kernel_launch(void* const* d_in, const int* in_sizes, int n_in,
                              void* d_out, int out_size, void* d_ws, size_t ws_size,
                              hipStream_t stream) {
  const float* src         = (const float*)d_in[0];
  const float* pos         = (const float*)d_in[1];
  const float* query_embed = (const float*)d_in[2];
  const float* cam_mask    = (const float*)d_in[3];
  const float* enc_qkv_w   = (const float*)d_in[4];
  const float* enc_qkv_b   = (const float*)d_in[5];
  const float* enc_out_w   = (const float*)d_in[6];
  const float* enc_out_b   = (const float*)d_in[7];
  const float* enc_ln1_g   = (const float*)d_in[8];
  const float* enc_ln1_b   = (const float*)d_in[9];
  const float* enc_ff1_w   = (const float*)d_in[10];
  const float* enc_ff1_b   = (const float*)d_in[11];
  const float* enc_ff2_w   = (const float*)d_in[12];
  const float* enc_ff2_b   = (const float*)d_in[13];
  const float* enc_ln2_g   = (const float*)d_in[14];
  const float* enc_ln2_b   = (const float*)d_in[15];
  const float* dec_sa_qkv_w= (const float*)d_in[16];
  const float* dec_sa_qkv_b= (const float*)d_in[17];
  const float* dec_sa_out_w= (const float*)d_in[18];
  const float* dec_sa_out_b= (const float*)d_in[19];
  const float* dec_ln1_g   = (const float*)d_in[20];
  const float* dec_ln1_b   = (const float*)d_in[21];
  const float* dec_ca_qkv_w= (const float*)d_in[22];
  const float* dec_ca_qkv_b= (const float*)d_in[23];
  const float* dec_ca_out_w= (const float*)d_in[24];
  const float* dec_ca_out_b= (const float*)d_in[25];
  const float* dec_ln2_g   = (const float*)d_in[26];
  const float* dec_ln2_b   = (const float*)d_in[27];
  const float* dec_ff1_w   = (const float*)d_in[28];
  const float* dec_ff1_b   = (const float*)d_in[29];
  const float* dec_ff2_w   = (const float*)d_in[30];
  const float* dec_ff2_b   = (const float*)d_in[31];
  const float* dec_ln3_g   = (const float*)d_in[32];
  const float* dec_ln3_b   = (const float*)d_in[33];
  const float* dec_norm_g  = (const float*)d_in[34];
  const float* dec_norm_b  = (const float*)d_in[35];

  // ---------------- workspace layout ----------------
  size_t off = 0;
  char* base = (char*)d_ws;
  auto af = [&](size_t n) { float* p = (float*)(base + off); off += n * 4; return p; };
  auto ab = [&](size_t n) { bf16*  p = (bf16*)(base + off);  off += n * 2; return p; };

  float* mem  = af(2097152);
  float* r1   = af(2097152);
  float* PO   = af(8388608);   // split-K / attn partials
  float* pm   = af(262144);
  float* pl   = af(262144);
  float* cmlog= af(655360);    // cam_mask * log2e
  float* pb   = af(1024);      // packed CA K/V biases
  float* tgt  = af(163840);
  float* tpr  = af(163840);
  bf16* memb  = ab(2097152);
  bf16* qkb   = ab(2097152);
  bf16* aob   = ab(2097152);
  bf16* ffb   = ab(16777216);
  bf16* bufQ  = ab(4194304);   // Q section + batched-K section
  bf16* bufK  = ab(4194304);   // CA K, both layers
  bf16* bufV  = ab(4194304);   // CA V^T, both layers (enc V^T uses [0..2M))
  bf16* bufVsa= ab(163840);    // SA V^T per layer
  bf16* tgtb  = ab(163840);
  bf16* tqkb  = ab(163840);
  bf16* taob  = ab(163840);
  bf16* tffb  = ab(1310720);
  bf16* w_enc_qkv = ab(393216);
  bf16* w_enc_out = ab(131072);
  bf16* w_enc_ff1 = ab(1048576);
  bf16* w_enc_ff2 = ab(1048576);
  bf16* w_sa_qkv  = ab(393216);
  bf16* w_sa_out  = ab(131072);
  bf16* w_ca_q    = ab(131072);   // [Q0;Q1]
  bf16* w_ca_kv   = ab(262144);   // [K0;K1;V0;V1]
  bf16* w_ca_out  = ab(131072);
  bf16* w_dec_ff1 = ab(1048576);
  bf16* w_dec_ff2 = ab(1048576);

  // (1/sqrt(32)) * log2(e) folded into Q projection
  const float qscale = 0.17677669529663687f * LOG2E;

  // ---- fused weight + src casts (CA qkv re-packed per-section) ----
  {
    CastArgs ca;
    const float* ins[NCAST] = {
        enc_qkv_w, enc_out_w, enc_ff1_w, enc_ff2_w,
        dec_sa_qkv_w, dec_sa_out_w,
        dec_ca_qkv_w,            // Q0
        dec_ca_qkv_w + 65536,    // K0
        dec_ca_qkv_w + 131072,   // V0
        dec_ca_qkv_w + 196608,   // Q1
        dec_ca_qkv_w + 262144,   // K1
        dec_ca_qkv_w + 327680,   // V1
        dec_ca_out_w, dec_ff1_w, dec_ff2_w, src};
    bf16* outs[NCAST] = {
        w_enc_qkv, w_enc_out, w_enc_ff1, w_enc_ff2,
        w_sa_qkv, w_sa_out,
        w_ca_q,              // Q0
        w_ca_kv,             // K0
        w_ca_kv + 131072,    // V0
        w_ca_q + 65536,      // Q1
        w_ca_kv + 65536,     // K1
        w_ca_kv + 196608,    // V1
        w_ca_out, w_dec_ff1, w_dec_ff2, memb};
    int n4s[NCAST] = {98304, 32768, 262144, 262144, 98304, 32768,
                      16384, 16384, 16384, 16384, 16384, 16384,
                      32768, 262144, 262144, 524288};
    int acc = 0;
    for (int s = 0; s < NCAST; ++s) {
      ca.in[s] = ins[s]; ca.out[s] = outs[s];
      acc += n4s[s]; ca.end4[s] = acc;
    }
    ca.nseg = NCAST;
    cast_multi<<<(acc + 255) / 256, 256, 0, stream>>>(ca, acc);
  }
  scale_f32_kernel<<<640, 256, 0, stream>>>(cam_mask, cmlog, LOG2E, 163840);
  hipMemcpyAsync(mem, src, (size_t)2097152 * 4, hipMemcpyDeviceToDevice, stream);
  // packed CA biases: [K0b;K1b;V0b;V1b]
  hipMemcpyAsync(pb,       dec_ca_qkv_b + 256,       1024, hipMemcpyDeviceToDevice, stream);
  hipMemcpyAsync(pb + 256, dec_ca_qkv_b + 768 + 256, 1024, hipMemcpyDeviceToDevice, stream);
  hipMemcpyAsync(pb + 512, dec_ca_qkv_b + 512,       1024, hipMemcpyDeviceToDevice, stream);
  hipMemcpyAsync(pb + 768, dec_ca_qkv_b + 768 + 512, 1024, hipMemcpyDeviceToDevice, stream);

  // GEMM launch helpers
  auto g64_f = [&](const bf16* A, const bf16* W, const float* bias, float* C,
                   int M, int N, int K) {
    mfma_gemm<64, 0, 1><<<dim3(M / 64, N / 64), 256, 0, stream>>>(
        A, W, bias, C, nullptr, M, N, K, 0, 1.f);
  };
  auto g64_head = [&](const bf16* A, const bf16* W, const float* bias, bf16* Cb,
                      int M, int N, int K, int HL, float qs) {
    mfma_gemm<64, 3, 1><<<dim3(M / 64, N / 64), 256, 0, stream>>>(
        A, W, bias, nullptr, Cb, M, N, K, HL, qs);
  };
  auto g64_headT = [&](const bf16* A, const bf16* W, const float* bias, bf16* Cb,
                       int M, int N, int K, int HL) {
    mfma_gemm<64, 5, 1><<<dim3(M / 64, N / 64), 256, 0, stream>>>(
        A, W, bias, nullptr, Cb, M, N, K, HL, 1.f);
  };
  auto g64_relu = [&](const bf16* A, const bf16* W, const float* bias, bf16* Cb,
                      int M, int N, int K) {
    mfma_gemm<64, 2, 1><<<dim3(M / 64, N / 64), 256, 0, stream>>>(
        A, W, bias, nullptr, Cb, M, N, K, 0, 1.f);
  };
  auto g128_relu = [&](const bf16* A, const bf16* W, const float* bias, bf16* Cb,
                       int M, int N, int K) {
    mfma_gemm<128, 2, 1><<<dim3(M / 128, N / 128), 256, 0, stream>>>(
        A, W, bias, nullptr, Cb, M, N, K, 0, 1.f);
  };

  // ---------------- encoder ----------------
  for (int i = 0; i < 2; ++i) {
    const bf16* wq = w_enc_qkv + (size_t)i * 196608;
    const float* qkvb = enc_qkv_b + (size_t)i * 768;
    add_bf16_kernel<<<2048, 256, 0, stream>>>(mem, pos, qkb, 524288);
    g64_head(qkb, wq, qkvb, bufQ, 8192, 512, 256, 1024, qscale);           // Q + K
    g64_headT(memb, wq + 131072, qkvb + 512, bufV, 8192, 256, 256, 1024);  // V^T
    // flash attention: 2-wave blocks, 2048 blocks -> full occupancy
    attn_mfma<0, 0, 2><<<dim3(64, 32), 128, 0, stream>>>(
        bufQ, bufQ + 2097152, bufV, nullptr, aob, nullptr, nullptr, nullptr,
        1024, 1024, 0);
    g64_f(aob, w_enc_out + (size_t)i * 65536, enc_out_b + i * 256, r1,
          8192, 256, 256);
    ln_kernel<<<8192, 256, 0, stream>>>(mem, r1, nullptr, 0, 0, nullptr,
                                        enc_ln1_g + i * 256, enc_ln1_b + i * 256,
                                        mem, memb);
    g128_relu(memb, w_enc_ff1 + (size_t)i * 524288, enc_ff1_b + i * 2048, ffb,
              8192, 2048, 256);
    mfma_gemm<128, 4, 4><<<dim3(64, 2, 4), 256, 0, stream>>>(
        ffb, w_enc_ff2 + (size_t)i * 524288, nullptr, PO, nullptr,
        8192, 256, 2048, 0, 1.f);
    ln_kernel<<<8192, 256, 0, stream>>>(mem, nullptr, PO, 4, 2097152,
                                        enc_ff2_b + i * 256,
                                        enc_ln2_g + i * 256, enc_ln2_b + i * 256,
                                        mem, memb);
  }

  // ---------------- decoder ----------------
  hipMemsetAsync(tgt, 0, (size_t)163840 * 4, stream);
  hipMemsetAsync(tgtb, 0, (size_t)163840 * 2, stream);
  add_bf16_kernel<<<2048, 256, 0, stream>>>(mem, pos, qkb, 524288);  // CA key input

  // Hoisted CA K/V projections (both layers, batched N=512)
  g64_head(qkb, w_ca_kv, pb, bufK, 8192, 512, 256, 1024, 1.f);             // K0|K1
  g64_headT(memb, w_ca_kv + 131072, pb + 512, bufV, 8192, 512, 256, 1024); // V0|V1

  for (int i = 0; i < 2; ++i) {
    const bf16* wsa = w_sa_qkv + (size_t)i * 196608;
    const float* sab = dec_sa_qkv_b + (size_t)i * 768;
    const float* cab = dec_ca_qkv_b + (size_t)i * 768;

    // self-attention
    add_bf16_kernel<<<160, 256, 0, stream>>>(tgt, query_embed, tqkb, 40960);
    g64_head(tqkb, wsa, sab, bufQ, 640, 512, 256, 80, qscale);             // Q + K
    g64_headT(tgtb, wsa + 131072, sab + 512, bufVsa, 640, 256, 256, 80);   // V^T
    attn_mfma<0, 0, 2><<<dim3(64, 3), 128, 0, stream>>>(
        bufQ, bufQ + 163840, bufVsa, nullptr, taob, nullptr, nullptr, nullptr,
        80, 80, 0);
    g64_f(taob, w_sa_out + (size_t)i * 65536, dec_sa_out_b + i * 256, tpr,
          640, 256, 256);
    ln_kernel<<<640, 256, 0, stream>>>(tgt, tpr, nullptr, 0, 0, nullptr,
                                       dec_ln1_g + i * 256, dec_ln1_b + i * 256,
                                       tgt, tgtb);
    // cross-attention (S split into 8 chunks of 128 + combine)
    add_bf16_kernel<<<160, 256, 0, stream>>>(tgt, query_embed, tqkb, 40960);
    g64_head(tqkb, w_ca_q + (size_t)i * 65536, cab, bufQ, 640, 256, 256, 80, qscale);
    attn_mfma<1, 1, 2><<<dim3(64, 3, 8), 128, 0, stream>>>(
        bufQ, bufK + (size_t)i * 2097152, bufV + (size_t)i * 2097152, cmlog,
        nullptr, PO, pm, pl, 80, 1024, 128);
    attn_combine<<<640, 256, 0, stream>>>(PO, pm, pl, taob, 80, 8);
    g64_f(taob, w_ca_out + (size_t)i * 65536, dec_ca_out_b + i * 256, tpr,
          640, 256, 256);
    ln_kernel<<<640, 256, 0, stream>>>(tgt, tpr, nullptr, 0, 0, nullptr,
                                       dec_ln2_g + i * 256, dec_ln2_b + i * 256,
                                       tgt, tgtb);
    // feed-forward
    g64_relu(tgtb, w_dec_ff1 + (size_t)i * 524288, dec_ff1_b + i * 2048, tffb,
             640, 2048, 256);
    mfma_gemm<64, 4, 4><<<dim3(10, 4, 4), 256, 0, stream>>>(
        tffb, w_dec_ff2 + (size_t)i * 524288, nullptr, PO, nullptr,
        640, 256, 2048, 0, 1.f);
    ln_kernel<<<640, 256, 0, stream>>>(tgt, nullptr, PO, 4, 163840,
                                       dec_ff2_b + i * 256,
                                       dec_ln3_g + i * 256, dec_ln3_b + i * 256,
                                       tgt, tgtb);
  }

  // final norm -> fp32 output
  ln_kernel<<<640, 256, 0, stream>>>(tgt, nullptr, nullptr, 0, 0, nullptr,
                                     dec_norm_g, dec_norm_b,
                                     (float*)d_out, nullptr);
}

// Round 9
// 433.801 us; speedup vs baseline: 1.2482x; 1.2482x over previous
//
#include <hip/hip_runtime.h>
#include <hip/hip_bf16.h>
#include <cstdint>
#include <cstddef>

typedef __hip_bfloat16 bf16;
typedef float f4 __attribute__((ext_vector_type(4)));
typedef float f32x4 __attribute__((ext_vector_type(4)));
typedef short s8v __attribute__((ext_vector_type(8)));
typedef unsigned short u16x4 __attribute__((ext_vector_type(4)));
typedef unsigned short u16x8 __attribute__((ext_vector_type(8)));

#define LN_EPS 1e-5f
#define LOG2E 1.4426950408889634f

// async global->LDS 16B per lane: lds dest = base + lane*16 (wave-uniform base)
__device__ __forceinline__ void async_cp16(const void* g, void* lds) {
  __builtin_amdgcn_global_load_lds(
      (const __attribute__((address_space(1))) unsigned int*)g,
      (__attribute__((address_space(3))) unsigned int*)lds, 16, 0, 0);
}

__device__ __forceinline__ uint32_t pkbf(float lo, float hi) {
  bf16 a = __float2bfloat16(lo), c = __float2bfloat16(hi);
  return (uint32_t)*(unsigned short*)&a | ((uint32_t)*(unsigned short*)&c << 16);
}

// ------------------------------------------------------------------
// fused multi-segment cast fp32 -> bf16
// ------------------------------------------------------------------
#define NCAST 16
struct CastArgs {
  const float* in[NCAST];
  bf16* out[NCAST];
  int end4[NCAST];
  int nseg;
};

__global__ __launch_bounds__(256) void cast_multi(CastArgs a, int total4) {
  int i = blockIdx.x * 256 + threadIdx.x;
  if (i >= total4) return;
  int s = 0;
  while (i >= a.end4[s]) ++s;
  int j = i - (s ? a.end4[s - 1] : 0);
  f4 v = ((const f4*)a.in[s])[j];
  u16x4 o;
#pragma unroll
  for (int c = 0; c < 4; ++c) {
    bf16 h = __float2bfloat16(v[c]);
    o[c] = *reinterpret_cast<unsigned short*>(&h);
  }
  ((u16x4*)a.out[s])[j] = o;
}

// scale fp32 array by constant (cam_mask * log2e)
__global__ __launch_bounds__(256) void scale_f32_kernel(const float* __restrict__ in,
                                                        float* __restrict__ out,
                                                        float s, int n4) {
  int i = blockIdx.x * 256 + threadIdx.x;
  if (i < n4) {
    f4 v = ((const f4*)in)[i];
    ((f4*)out)[i] = v * s;
  }
}

// ------------------------------------------------------------------
// add fp32 + fp32 -> bf16
// ------------------------------------------------------------------
__global__ __launch_bounds__(256) void add_bf16_kernel(const float* __restrict__ a,
                                                       const float* __restrict__ b,
                                                       bf16* __restrict__ out, int n4) {
  int i = blockIdx.x * 256 + threadIdx.x;
  if (i < n4) {
    f4 x = ((const f4*)a)[i];
    f4 y = ((const f4*)b)[i];
    u16x4 o;
#pragma unroll
    for (int j = 0; j < 4; ++j) {
      bf16 h = __float2bfloat16(x[j] + y[j]);
      o[j] = *reinterpret_cast<unsigned short*>(&h);
    }
    ((u16x4*)out)[i] = o;
  }
}

// ------------------------------------------------------------------
// MFMA GEMM: C[M,N] = A[M,K] @ W[N,K]^T (+ bias[N])
// global_load_lds staging, linear LDS [TB][64] bf16, XOR-swizzled source
// columns + swizzled ds_read (involution: slot ^= row&7).
// MODE: 0 f32, 2 bf16+relu, 3 bf16 head layout (sec0 scaled by qscale),
//       4 f32 split-K partial,
//       5 bf16 transposed head layout (V^T) via LDS-transpose epilogue
//         (TB must be 64 for MODE 5)
// ------------------------------------------------------------------
template <int TB, int MODE, int SPLITK>
__global__ __launch_bounds__(256, 2) void mfma_gemm(
    const bf16* __restrict__ A, const bf16* __restrict__ W,
    const float* __restrict__ bias, float* __restrict__ C,
    bf16* __restrict__ Cb, int M, int N, int K, int HL, float qscale) {
  constexpr int WM = TB / 2, WN = TB / 2;
  constexpr int MR = WM / 16, NR = WN / 16;
  constexpr int NCH = TB / 32;
  __shared__ __attribute__((aligned(16))) unsigned short SH[TB * 128];
  unsigned short (*As)[64] = (unsigned short(*)[64])SH;
  unsigned short (*Ws)[64] = (unsigned short(*)[64])(SH + TB * 64);
  const int tid = threadIdx.x;
  const int lane = tid & 63, wave = tid >> 6;
  const int wr = wave >> 1, wc = wave & 1;
  const int bm = blockIdx.x * TB, bn = blockIdx.y * TB;
  const int fr = lane & 15, fo = lane >> 4;
  const int srowi = lane >> 3;
  const int slot = lane & 7;
  const int gcol = (slot ^ srowi) * 8;

  const int kchunk = K / SPLITK;
  const int kbeg = (SPLITK > 1) ? blockIdx.z * kchunk : 0;

  f32x4 acc[MR][NR] = {};

  for (int k0 = kbeg; k0 < kbeg + kchunk; k0 += 64) {
    __syncthreads();
#pragma unroll
    for (int c = 0; c < NCH; ++c) {
      int rbase = wave * (TB / 4) + c * 8;
      int row = rbase + srowi;
      async_cp16(A + (size_t)(bm + row) * K + k0 + gcol, &As[rbase][0]);
      async_cp16(W + (size_t)(bn + row) * K + k0 + gcol, &Ws[rbase][0]);
    }
    __syncthreads();
#pragma unroll
    for (int ks = 0; ks < 2; ++ks) {
      s8v a[MR], b[NR];
#pragma unroll
      for (int mi = 0; mi < MR; ++mi) {
        int row = wr * WM + mi * 16 + fr;
        a[mi] = *(const s8v*)((const char*)&As[0][0] + row * 128 +
                              ((ks * 64 + fo * 16) ^ ((row & 7) << 4)));
      }
#pragma unroll
      for (int ni = 0; ni < NR; ++ni) {
        int row = wc * WN + ni * 16 + fr;
        b[ni] = *(const s8v*)((const char*)&Ws[0][0] + row * 128 +
                              ((ks * 64 + fo * 16) ^ ((row & 7) << 4)));
      }
#pragma unroll
      for (int mi = 0; mi < MR; ++mi)
#pragma unroll
        for (int ni = 0; ni < NR; ++ni)
          acc[mi][ni] = __builtin_amdgcn_mfma_f32_16x16x32_bf16(
              a[mi], b[ni], acc[mi][ni], 0, 0, 0);
    }
  }

  const int r0 = (lane >> 4) * 4;

  if (MODE == 5) {
    // LDS-transpose epilogue: T[col][row] (64x72 u16), then 16B chunk stores
    __syncthreads();
    unsigned short (*T)[72] = (unsigned short(*)[72])SH;
#pragma unroll
    for (int mi = 0; mi < MR; ++mi)
#pragma unroll
      for (int ni = 0; ni < NR; ++ni) {
        int colL = wc * WN + ni * 16 + fr;
        float bv = bias[bn + colL];
#pragma unroll
        for (int r = 0; r < 4; ++r) {
          int rowL = wr * WM + mi * 16 + r0 + r;
          bf16 hv = __float2bfloat16(acc[mi][ni][r] + bv);
          T[colL][rowL] = *(unsigned short*)&hv;
        }
      }
    __syncthreads();
    const int lbase = bm >> 3;
#pragma unroll
    for (int jj = 0; jj < 2; ++jj) {
      int cid = tid * 2 + jj;
      int colL = cid >> 3, bb = cid & 7;
      int c = bn + colL;
      int sec = c >> 8, hh = (c >> 5) & 7, d = c & 31;
      u16x8 v;
#pragma unroll
      for (int l = 0; l < 8; ++l) v[l] = T[colL][bb + 8 * l];
      *(u16x8*)(Cb + (size_t)sec * ((size_t)64 * 32 * HL) +
                ((size_t)(bb * 8 + hh) * 32 + d) * HL + lbase) = v;
    }
    return;
  }

  float* Cz = (MODE == 4) ? C + (size_t)blockIdx.z * M * N : C;
#pragma unroll
  for (int mi = 0; mi < MR; ++mi) {
#pragma unroll
    for (int ni = 0; ni < NR; ++ni) {
      int col = bn + wc * WN + ni * 16 + fr;
      float bv = (MODE == 4) ? 0.f : bias[col];
#pragma unroll
      for (int r = 0; r < 4; ++r) {
        int row = bm + wr * WM + mi * 16 + r0 + r;
        float t = acc[mi][ni][r] + bv;
        if (MODE == 2) t = fmaxf(t, 0.f);
        if (MODE == 0) {
          C[(size_t)row * N + col] = t;
        } else if (MODE == 4) {
          Cz[(size_t)row * N + col] = t;
        } else if (MODE == 3) {
          int l = row >> 3, bb = row & 7;
          int sec = col >> 8, hh = (col >> 5) & 7, d = col & 31;
          if (sec == 0) t *= qscale;
          Cb[(size_t)sec * ((size_t)64 * HL * 32) +
             ((size_t)(bb * 8 + hh) * HL + l) * 32 + d] = __float2bfloat16(t);
        } else {
          Cb[(size_t)row * N + col] = __float2bfloat16(t);
        }
      }
    }
  }
}

// ------------------------------------------------------------------
// Swapped-operand MFMA flash attention (in-lane softmax, no barriers).
// Qh: (64, L, 32) bf16, pre-scaled by (1/sqrt(32))*log2e.
// Kh: (64, S, 32) bf16. VhT: (64, 32, S) bf16 (transposed head layout).
// bias (optional): (8, L, S) fp32, pre-scaled by log2e.
// NW waves/block, 16 q-rows per wave.
// grid (64 bh, ceil(L/(NW*16)), nz). block NW*64.
// ------------------------------------------------------------------
template <int HAS_BIAS, int PARTIAL, int NW>
__global__ __launch_bounds__(NW * 64, 4) void attn_mfma(
    const bf16* __restrict__ Qh, const bf16* __restrict__ Kh,
    const bf16* __restrict__ VhT, const float* __restrict__ bias,
    bf16* __restrict__ O, float* __restrict__ PO, float* __restrict__ PM,
    float* __restrict__ PL, int L, int S, int SC) {
  __shared__ __attribute__((aligned(16))) uint32_t Ps2[NW][16][36];
  const int tid = threadIdx.x;
  const int lane = tid & 63, wave = tid >> 6;
  const int fr = lane & 15, fo = lane >> 4;
  const int bh = blockIdx.x;
  const int b = bh >> 3, h = bh & 7;
  const int q0 = blockIdx.y * (NW * 16) + wave * 16;
  const int q = q0 + fr;

  const int cz = PARTIAL ? blockIdx.z : 0;
  const int sb = PARTIAL ? cz * SC : 0;
  const int se = PARTIAL ? min(S, sb + SC) : S;

  s8v qf = {};
  if (q < L) qf = *(const s8v*)(Qh + ((size_t)bh * L + q) * 32 + fo * 8);

  const float* brow = nullptr;
  if (HAS_BIAS) brow = bias + ((size_t)b * L + (q < L ? q : L - 1)) * S;

  float m = -1e30f, lsum = 0.f;
  f32x4 oacc[2] = {};

  // K fragment loader: kf[kb] = K[key = s0 + kb*16 + fr][d = fo*8..+7]
  s8v kf[4];
#pragma unroll
  for (int kb = 0; kb < 4; ++kb)
    kf[kb] = *(const s8v*)(Kh + ((size_t)bh * S + sb + kb * 16 + fr) * 32 + fo * 8);

  for (int s0 = sb; s0 < se; s0 += 64) {
    const bool more = (s0 + 64 < se);
    s8v kn[4];
    if (more) {
#pragma unroll
      for (int kb = 0; kb < 4; ++kb)
        kn[kb] = *(const s8v*)(Kh + ((size_t)bh * S + s0 + 64 + kb * 16 + fr) * 32 + fo * 8);
    }
    // V^T fragments: vf[dh][ks] = V^T[d = dh*16 + fr][key = s0 + ks*32 + fo*8..+7]
    s8v vf[2][2];
#pragma unroll
    for (int dh = 0; dh < 2; ++dh)
#pragma unroll
      for (int ks = 0; ks < 2; ++ks)
        vf[dh][ks] = *(const s8v*)(VhT + ((size_t)bh * 32 + dh * 16 + fr) * S +
                                   s0 + ks * 32 + fo * 8);
    f4 bias4[4];
    if (HAS_BIAS) {
#pragma unroll
      for (int kb = 0; kb < 4; ++kb)
        bias4[kb] = *(const f4*)(brow + s0 + kb * 16 + 4 * fo);
    }

    // QK^T swapped: sa[kb] = S^T[key-block][q]; col=q=fr, row=4*fo+r
    f32x4 sa[4];
#pragma unroll
    for (int kb = 0; kb < 4; ++kb) {
      f32x4 z = {};
      sa[kb] = __builtin_amdgcn_mfma_f32_16x16x32_bf16(kf[kb], qf, z, 0, 0, 0);
    }

    float lg[16];
#pragma unroll
    for (int kb = 0; kb < 4; ++kb)
#pragma unroll
      for (int r = 0; r < 4; ++r)
        lg[kb * 4 + r] = HAS_BIAS ? sa[kb][r] + bias4[kb][r] : sa[kb][r];

    if (s0 + 64 > se) {  // boundary tile: mask invalid keys
#pragma unroll
      for (int kb = 0; kb < 4; ++kb)
#pragma unroll
        for (int r = 0; r < 4; ++r)
          if (s0 + kb * 16 + 4 * fo + r >= se) lg[kb * 4 + r] = -1e30f;
    }

    // tile max: in-lane chain + 2 cross-fo shuffles
    float tm = lg[0];
#pragma unroll
    for (int i = 1; i < 16; ++i) tm = fmaxf(tm, lg[i]);
    tm = fmaxf(tm, __shfl_xor(tm, 16));
    tm = fmaxf(tm, __shfl_xor(tm, 32));

    // deferred rescale (wave-uniform)
    if (__any(tm > m + 8.f)) {
      float nm = fmaxf(m, tm);
      float rs = exp2f(m - nm);
      m = nm;
      lsum *= rs;
#pragma unroll
      for (int r = 0; r < 4; ++r) { oacc[0][r] *= rs; oacc[1][r] *= rs; }
    }

    float pr[16];
    float ps = 0.f;
#pragma unroll
    for (int i = 0; i < 16; ++i) {
      pr[i] = exp2f(lg[i] - m);
      ps += pr[i];
    }
    lsum += ps;  // partial (this lane's 16 keys); cross-fo reduced at end

    // pack P -> per-wave LDS: row=q(fr), u32 idx = key/2
#pragma unroll
    for (int kb = 0; kb < 4; ++kb) {
      uint32_t w0 = pkbf(pr[kb * 4 + 0], pr[kb * 4 + 1]);
      uint32_t w1 = pkbf(pr[kb * 4 + 2], pr[kb * 4 + 3]);
      uint64_t w = (uint64_t)w0 | ((uint64_t)w1 << 32);
      *(uint64_t*)&Ps2[wave][fr][kb * 8 + 2 * fo] = w;
    }

    // P^T fragments: pf[ks] lane holds P[q=fr][key = ks*32 + fo*8..+7]
    s8v pf[2];
#pragma unroll
    for (int ks = 0; ks < 2; ++ks)
      pf[ks] = *(const s8v*)&Ps2[wave][fr][ks * 16 + 4 * fo];

    // PV swapped: oacc[dh] = O^T[d][q], col=q=fr, row d = dh*16 + 4*fo + r
#pragma unroll
    for (int dh = 0; dh < 2; ++dh)
#pragma unroll
      for (int ks = 0; ks < 2; ++ks)
        oacc[dh] = __builtin_amdgcn_mfma_f32_16x16x32_bf16(
            vf[dh][ks], pf[ks], oacc[dh], 0, 0, 0);

    if (more) {
#pragma unroll
      for (int kb = 0; kb < 4; ++kb) kf[kb] = kn[kb];
    }
  }

  // full row-sum across the 4 fo-lanes
  lsum += __shfl_xor(lsum, 16);
  lsum += __shfl_xor(lsum, 32);

  if (q < L) {
    if (PARTIAL) {
      size_t pi = ((size_t)cz * 64 + bh) * L + q;
      float* po = PO + pi * 32;
#pragma unroll
      for (int dh = 0; dh < 2; ++dh) {
        f4 t;
#pragma unroll
        for (int r = 0; r < 4; ++r) t[r] = oacc[dh][r];
        *(f4*)(po + dh * 16 + 4 * fo) = t;
      }
      if (fo == 0) { PM[pi] = m; PL[pi] = lsum; }
    } else {
      float inv = 1.f / lsum;
      bf16* op = O + ((size_t)q * 8 + b) * 256 + h * 32;
#pragma unroll
      for (int dh = 0; dh < 2; ++dh) {
        uint32_t w0 = pkbf(oacc[dh][0] * inv, oacc[dh][1] * inv);
        uint32_t w1 = pkbf(oacc[dh][2] * inv, oacc[dh][3] * inv);
        *(uint32_t*)(op + dh * 16 + 4 * fo) = w0;
        *(uint32_t*)(op + dh * 16 + 4 * fo + 2) = w1;
      }
    }
  }
}

// ------------------------------------------------------------------
// combine NC S-chunk partials -> O bf16 (thread per (bh,q,d))
// NOTE: PM/PL are in log2 domain (exp2 weights).
// ------------------------------------------------------------------
__global__ __launch_bounds__(256) void attn_combine(
    const float* __restrict__ PO, const float* __restrict__ PM,
    const float* __restrict__ PL, bf16* __restrict__ O, int L, int NC) {
  int gid = blockIdx.x * 256 + threadIdx.x;
  if (gid >= 64 * L * 32) return;
  int d = gid & 31;
  int rem = gid >> 5;
  int q = rem % L, bh = rem / L;
  int b = bh >> 3, h = bh & 7;
  float M = -1e30f;
  for (int c = 0; c < NC; ++c) M = fmaxf(M, PM[((size_t)c * 64 + bh) * L + q]);
  float lsum = 0.f, o = 0.f;
  for (int c = 0; c < NC; ++c) {
    size_t pi = ((size_t)c * 64 + bh) * L + q;
    float w = exp2f(PM[pi] - M);
    lsum += PL[pi] * w;
    o += PO[pi * 32 + d] * w;
  }
  O[((size_t)q * 8 + b) * 256 + h * 32 + d] = __float2bfloat16(o / lsum);
}

// ------------------------------------------------------------------
// LayerNorm over last dim (256): v = x (+res) (+Σ parts) (+gbias);
// out = LN(v)*g + b ; dual output (f32 + bf16)
// ------------------------------------------------------------------
__global__ __launch_bounds__(256) void ln_kernel(
    const float* __restrict__ x, const float* __restrict__ res,
    const float* __restrict__ parts, int nparts, int pstride,
    const float* __restrict__ gbias,
    const float* __restrict__ g, const float* __restrict__ b,
    float* __restrict__ out, bf16* __restrict__ outb) {
  const int row = blockIdx.x, tid = threadIdx.x;
  size_t idx = (size_t)row * 256 + tid;
  float v = x[idx];
  if (res) v += res[idx];
  if (parts) {
    for (int z = 0; z < nparts; ++z) v += parts[(size_t)z * pstride + idx];
  }
  if (gbias) v += gbias[tid];
  float s = v, s2 = v * v;
#pragma unroll
  for (int off = 32; off >= 1; off >>= 1) {
    s += __shfl_down(s, off);
    s2 += __shfl_down(s2, off);
  }
  __shared__ float red[8];
  int wv = tid >> 6;
  if ((tid & 63) == 0) { red[wv] = s; red[4 + wv] = s2; }
  __syncthreads();
  if (tid == 0) {
    float ts = red[0] + red[1] + red[2] + red[3];
    float ts2 = red[4] + red[5] + red[6] + red[7];
    float mu = ts * (1.f / 256.f);
    float var = ts2 * (1.f / 256.f) - mu * mu;
    red[0] = mu;
    red[1] = rsqrtf(var + LN_EPS);
  }
  __syncthreads();
  float y = (v - red[0]) * red[1] * g[tid] + b[tid];
  if (out) out[idx] = y;
  if (outb) outb[idx] = __float2bfloat16(y);
}

// ------------------------------------------------------------------
// Host orchestration
// ------------------------------------------------------------------
extern "C" void kernel_launch(void* const* d_in, const int* in_sizes, int n_in,
                              void* d_out, int out_size, void* d_ws, size_t ws_size,
                              hipStream_t stream) {
  const float* src         = (const float*)d_in[0];
  const float* pos         = (const float*)d_in[1];
  const float* query_embed = (const float*)d_in[2];
  const float* cam_mask    = (const float*)d_in[3];
  const float* enc_qkv_w   = (const float*)d_in[4];
  const float* enc_qkv_b   = (const float*)d_in[5];
  const float* enc_out_w   = (const float*)d_in[6];
  const float* enc_out_b   = (const float*)d_in[7];
  const float* enc_ln1_g   = (const float*)d_in[8];
  const float* enc_ln1_b   = (const float*)d_in[9];
  const float* enc_ff1_w   = (const float*)d_in[10];
  const float* enc_ff1_b   = (const float*)d_in[11];
  const float* enc_ff2_w   = (const float*)d_in[12];
  const float* enc_ff2_b   = (const float*)d_in[13];
  const float* enc_ln2_g   = (const float*)d_in[14];
  const float* enc_ln2_b   = (const float*)d_in[15];
  const float* dec_sa_qkv_w= (const float*)d_in[16];
  const float* dec_sa_qkv_b= (const float*)d_in[17];
  const float* dec_sa_out_w= (const float*)d_in[18];
  const float* dec_sa_out_b= (const float*)d_in[19];
  const float* dec_ln1_g   = (const float*)d_in[20];
  const float* dec_ln1_b   = (const float*)d_in[21];
  const float* dec_ca_qkv_w= (const float*)d_in[22];
  const float* dec_ca_qkv_b= (const float*)d_in[23];
  const float* dec_ca_out_w= (const float*)d_in[24];
  const float* dec_ca_out_b= (const float*)d_in[25];
  const float* dec_ln2_g   = (const float*)d_in[26];
  const float* dec_ln2_b   = (const float*)d_in[27];
  const float* dec_ff1_w   = (const float*)d_in[28];
  const float* dec_ff1_b   = (const float*)d_in[29];
  const float* dec_ff2_w   = (const float*)d_in[30];
  const float* dec_ff2_b   = (const float*)d_in[31];
  const float* dec_ln3_g   = (const float*)d_in[32];
  const float* dec_ln3_b   = (const float*)d_in[33];
  const float* dec_norm_g  = (const float*)d_in[34];
  const float* dec_norm_b  = (const float*)d_in[35];

  // ---------------- workspace layout ----------------
  size_t off = 0;
  char* base = (char*)d_ws;
  auto af = [&](size_t n) { float* p = (float*)(base + off); off += n * 4; return p; };
  auto ab = [&](size_t n) { bf16*  p = (bf16*)(base + off);  off += n * 2; return p; };

  float* mem  = af(2097152);
  float* r1   = af(2097152);
  float* PO   = af(8388608);   // split-K / attn partials
  float* pm   = af(262144);
  float* pl   = af(262144);
  float* cmlog= af(655360);    // cam_mask * log2e
  float* pb   = af(1024);      // packed CA K/V biases
  float* tgt  = af(163840);
  float* tpr  = af(163840);
  bf16* memb  = ab(2097152);
  bf16* qkb   = ab(2097152);
  bf16* aob   = ab(2097152);
  bf16* ffb   = ab(16777216);
  bf16* bufQ  = ab(4194304);   // Q section + batched-K section
  bf16* bufK  = ab(4194304);   // CA K, both layers
  bf16* bufV  = ab(4194304);   // CA V^T, both layers (enc V^T uses [0..2M))
  bf16* bufVsa= ab(163840);    // SA V^T per layer
  bf16* tgtb  = ab(163840);
  bf16* tqkb  = ab(163840);
  bf16* taob  = ab(163840);
  bf16* tffb  = ab(1310720);
  bf16* w_enc_qkv = ab(393216);
  bf16* w_enc_out = ab(131072);
  bf16* w_enc_ff1 = ab(1048576);
  bf16* w_enc_ff2 = ab(1048576);
  bf16* w_sa_qkv  = ab(393216);
  bf16* w_sa_out  = ab(131072);
  bf16* w_ca_q    = ab(131072);   // [Q0;Q1]
  bf16* w_ca_kv   = ab(262144);   // [K0;K1;V0;V1]
  bf16* w_ca_out  = ab(131072);
  bf16* w_dec_ff1 = ab(1048576);
  bf16* w_dec_ff2 = ab(1048576);

  // (1/sqrt(32)) * log2(e) folded into Q projection
  const float qscale = 0.17677669529663687f * LOG2E;

  // ---- fused weight + src casts (CA qkv re-packed per-section) ----
  {
    CastArgs ca;
    const float* ins[NCAST] = {
        enc_qkv_w, enc_out_w, enc_ff1_w, enc_ff2_w,
        dec_sa_qkv_w, dec_sa_out_w,
        dec_ca_qkv_w,            // Q0
        dec_ca_qkv_w + 65536,    // K0
        dec_ca_qkv_w + 131072,   // V0
        dec_ca_qkv_w + 196608,   // Q1
        dec_ca_qkv_w + 262144,   // K1
        dec_ca_qkv_w + 327680,   // V1
        dec_ca_out_w, dec_ff1_w, dec_ff2_w, src};
    bf16* outs[NCAST] = {
        w_enc_qkv, w_enc_out, w_enc_ff1, w_enc_ff2,
        w_sa_qkv, w_sa_out,
        w_ca_q,              // Q0
        w_ca_kv,             // K0
        w_ca_kv + 131072,    // V0
        w_ca_q + 65536,      // Q1
        w_ca_kv + 65536,     // K1
        w_ca_kv + 196608,    // V1
        w_ca_out, w_dec_ff1, w_dec_ff2, memb};
    int n4s[NCAST] = {98304, 32768, 262144, 262144, 98304, 32768,
                      16384, 16384, 16384, 16384, 16384, 16384,
                      32768, 262144, 262144, 524288};
    int acc = 0;
    for (int s = 0; s < NCAST; ++s) {
      ca.in[s] = ins[s]; ca.out[s] = outs[s];
      acc += n4s[s]; ca.end4[s] = acc;
    }
    ca.nseg = NCAST;
    cast_multi<<<(acc + 255) / 256, 256, 0, stream>>>(ca, acc);
  }
  scale_f32_kernel<<<640, 256, 0, stream>>>(cam_mask, cmlog, LOG2E, 163840);
  hipMemcpyAsync(mem, src, (size_t)2097152 * 4, hipMemcpyDeviceToDevice, stream);
  // packed CA biases: [K0b;K1b;V0b;V1b]
  hipMemcpyAsync(pb,       dec_ca_qkv_b + 256,       1024, hipMemcpyDeviceToDevice, stream);
  hipMemcpyAsync(pb + 256, dec_ca_qkv_b + 768 + 256, 1024, hipMemcpyDeviceToDevice, stream);
  hipMemcpyAsync(pb + 512, dec_ca_qkv_b + 512,       1024, hipMemcpyDeviceToDevice, stream);
  hipMemcpyAsync(pb + 768, dec_ca_qkv_b + 768 + 512, 1024, hipMemcpyDeviceToDevice, stream);

  // GEMM launch helpers
  auto g64_f = [&](const bf16* A, const bf16* W, const float* bias, float* C,
                   int M, int N, int K) {
    mfma_gemm<64, 0, 1><<<dim3(M / 64, N / 64), 256, 0, stream>>>(
        A, W, bias, C, nullptr, M, N, K, 0, 1.f);
  };
  auto g64_head = [&](const bf16* A, const bf16* W, const float* bias, bf16* Cb,
                      int M, int N, int K, int HL, float qs) {
    mfma_gemm<64, 3, 1><<<dim3(M / 64, N / 64), 256, 0, stream>>>(
        A, W, bias, nullptr, Cb, M, N, K, HL, qs);
  };
  auto g64_headT = [&](const bf16* A, const bf16* W, const float* bias, bf16* Cb,
                       int M, int N, int K, int HL) {
    mfma_gemm<64, 5, 1><<<dim3(M / 64, N / 64), 256, 0, stream>>>(
        A, W, bias, nullptr, Cb, M, N, K, HL, 1.f);
  };
  auto g64_relu = [&](const bf16* A, const bf16* W, const float* bias, bf16* Cb,
                      int M, int N, int K) {
    mfma_gemm<64, 2, 1><<<dim3(M / 64, N / 64), 256, 0, stream>>>(
        A, W, bias, nullptr, Cb, M, N, K, 0, 1.f);
  };
  auto g128_relu = [&](const bf16* A, const bf16* W, const float* bias, bf16* Cb,
                       int M, int N, int K) {
    mfma_gemm<128, 2, 1><<<dim3(M / 128, N / 128), 256, 0, stream>>>(
        A, W, bias, nullptr, Cb, M, N, K, 0, 1.f);
  };

  // ---------------- encoder ----------------
  for (int i = 0; i < 2; ++i) {
    const bf16* wq = w_enc_qkv + (size_t)i * 196608;
    const float* qkvb = enc_qkv_b + (size_t)i * 768;
    add_bf16_kernel<<<2048, 256, 0, stream>>>(mem, pos, qkb, 524288);
    g64_head(qkb, wq, qkvb, bufQ, 8192, 512, 256, 1024, qscale);           // Q + K
    g64_headT(memb, wq + 131072, qkvb + 512, bufV, 8192, 256, 256, 1024);  // V^T
    attn_mfma<0, 0, 4><<<dim3(64, 16), 256, 0, stream>>>(
        bufQ, bufQ + 2097152, bufV, nullptr, aob, nullptr, nullptr, nullptr,
        1024, 1024, 0);
    g64_f(aob, w_enc_out + (size_t)i * 65536, enc_out_b + i * 256, r1,
          8192, 256, 256);
    ln_kernel<<<8192, 256, 0, stream>>>(mem, r1, nullptr, 0, 0, nullptr,
                                        enc_ln1_g + i * 256, enc_ln1_b + i * 256,
                                        mem, memb);
    g128_relu(memb, w_enc_ff1 + (size_t)i * 524288, enc_ff1_b + i * 2048, ffb,
              8192, 2048, 256);
    mfma_gemm<128, 4, 4><<<dim3(64, 2, 4), 256, 0, stream>>>(
        ffb, w_enc_ff2 + (size_t)i * 524288, nullptr, PO, nullptr,
        8192, 256, 2048, 0, 1.f);
    ln_kernel<<<8192, 256, 0, stream>>>(mem, nullptr, PO, 4, 2097152,
                                        enc_ff2_b + i * 256,
                                        enc_ln2_g + i * 256, enc_ln2_b + i * 256,
                                        mem, memb);
  }

  // ---------------- decoder ----------------
  hipMemsetAsync(tgt, 0, (size_t)163840 * 4, stream);
  hipMemsetAsync(tgtb, 0, (size_t)163840 * 2, stream);
  add_bf16_kernel<<<2048, 256, 0, stream>>>(mem, pos, qkb, 524288);  // CA key input

  // Hoisted CA K/V projections (both layers, batched N=512)
  g64_head(qkb, w_ca_kv, pb, bufK, 8192, 512, 256, 1024, 1.f);             // K0|K1
  g64_headT(memb, w_ca_kv + 131072, pb + 512, bufV, 8192, 512, 256, 1024); // V0|V1

  for (int i = 0; i < 2; ++i) {
    const bf16* wsa = w_sa_qkv + (size_t)i * 196608;
    const float* sab = dec_sa_qkv_b + (size_t)i * 768;
    const float* cab = dec_ca_qkv_b + (size_t)i * 768;

    // self-attention
    add_bf16_kernel<<<160, 256, 0, stream>>>(tgt, query_embed, tqkb, 40960);
    g64_head(tqkb, wsa, sab, bufQ, 640, 512, 256, 80, qscale);             // Q + K
    g64_headT(tgtb, wsa + 131072, sab + 512, bufVsa, 640, 256, 256, 80);   // V^T
    attn_mfma<0, 0, 1><<<dim3(64, 5), 64, 0, stream>>>(
        bufQ, bufQ + 163840, bufVsa, nullptr, taob, nullptr, nullptr, nullptr,
        80, 80, 0);
    g64_f(taob, w_sa_out + (size_t)i * 65536, dec_sa_out_b + i * 256, tpr,
          640, 256, 256);
    ln_kernel<<<640, 256, 0, stream>>>(tgt, tpr, nullptr, 0, 0, nullptr,
                                       dec_ln1_g + i * 256, dec_ln1_b + i * 256,
                                       tgt, tgtb);
    // cross-attention (S split into 8 chunks of 128 + combine)
    add_bf16_kernel<<<160, 256, 0, stream>>>(tgt, query_embed, tqkb, 40960);
    g64_head(tqkb, w_ca_q + (size_t)i * 65536, cab, bufQ, 640, 256, 256, 80, qscale);
    attn_mfma<1, 1, 1><<<dim3(64, 5, 8), 64, 0, stream>>>(
        bufQ, bufK + (size_t)i * 2097152, bufV + (size_t)i * 2097152, cmlog,
        nullptr, PO, pm, pl, 80, 1024, 128);
    attn_combine<<<640, 256, 0, stream>>>(PO, pm, pl, taob, 80, 8);
    g64_f(taob, w_ca_out + (size_t)i * 65536, dec_ca_out_b + i * 256, tpr,
          640, 256, 256);
    ln_kernel<<<640, 256, 0, stream>>>(tgt, tpr, nullptr, 0, 0, nullptr,
                                       dec_ln2_g + i * 256, dec_ln2_b + i * 256,
                                       tgt, tgtb);
    // feed-forward
    g64_relu(tgtb, w_dec_ff1 + (size_t)i * 524288, dec_ff1_b + i * 2048, tffb,
             640, 2048, 256);
    mfma_gemm<64, 4, 4><<<dim3(10, 4, 4), 256, 0, stream>>>(
        tffb, w_dec_ff2 + (size_t)i * 524288, nullptr, PO, nullptr,
        640, 256, 2048, 0, 1.f);
    ln_kernel<<<640, 256, 0, stream>>>(tgt, nullptr, PO, 4, 163840,
                                       dec_ff2_b + i * 256,
                                       dec_ln3_g + i * 256, dec_ln3_b + i * 256,
                                       tgt, tgtb);
  }

  // final norm -> fp32 output
  ln_kernel<<<640, 256, 0, stream>>>(tgt, nullptr, nullptr, 0, 0, nullptr,
                                     dec_norm_g, dec_norm_b,
                                     (float*)d_out, nullptr);
}

// Round 10
// 431.789 us; speedup vs baseline: 1.2540x; 1.0047x over previous
//
#include <hip/hip_runtime.h>
#include <hip/hip_bf16.h>
#include <cstdint>
#include <cstddef>

typedef __hip_bfloat16 bf16;
typedef float f4 __attribute__((ext_vector_type(4)));
typedef float f32x4 __attribute__((ext_vector_type(4)));
typedef short s8v __attribute__((ext_vector_type(8)));
typedef unsigned short u16x4 __attribute__((ext_vector_type(4)));
typedef unsigned short u16x8 __attribute__((ext_vector_type(8)));

#define LN_EPS 1e-5f
#define LOG2E 1.4426950408889634f

// raw v_exp_f32 (input in log2 domain)
#if __has_builtin(__builtin_amdgcn_exp2f)
__device__ __forceinline__ float EXP2(float x) { return __builtin_amdgcn_exp2f(x); }
#else
__device__ __forceinline__ float EXP2(float x) {
  float r; asm("v_exp_f32 %0, %1" : "=v"(r) : "v"(x)); return r;
}
#endif

// async global->LDS 16B per lane: lds dest = base + lane*16 (wave-uniform base)
__device__ __forceinline__ void async_cp16(const void* g, void* lds) {
  __builtin_amdgcn_global_load_lds(
      (const __attribute__((address_space(1))) unsigned int*)g,
      (__attribute__((address_space(3))) unsigned int*)lds, 16, 0, 0);
}

// pack 2 floats -> 2 bf16 in a u32 (round-half-up + byte perm: 3 VALU ops)
__device__ __forceinline__ uint32_t pkbf(float lo, float hi) {
#if __has_builtin(__builtin_amdgcn_perm)
  uint32_t l = __builtin_bit_cast(uint32_t, lo) + 0x8000u;
  uint32_t h = __builtin_bit_cast(uint32_t, hi) + 0x8000u;
  return __builtin_amdgcn_perm(h, l, 0x07060302u);
#else
  uint32_t l = __builtin_bit_cast(uint32_t, lo) + 0x8000u;
  uint32_t h = __builtin_bit_cast(uint32_t, hi) + 0x8000u;
  return (l >> 16) | (h & 0xFFFF0000u);
#endif
}

// ------------------------------------------------------------------
// fused multi-segment cast fp32 -> bf16
// ------------------------------------------------------------------
#define NCAST 16
struct CastArgs {
  const float* in[NCAST];
  bf16* out[NCAST];
  int end4[NCAST];
  int nseg;
};

__global__ __launch_bounds__(256) void cast_multi(CastArgs a, int total4) {
  int i = blockIdx.x * 256 + threadIdx.x;
  if (i >= total4) return;
  int s = 0;
  while (i >= a.end4[s]) ++s;
  int j = i - (s ? a.end4[s - 1] : 0);
  f4 v = ((const f4*)a.in[s])[j];
  u16x4 o;
#pragma unroll
  for (int c = 0; c < 4; ++c) {
    bf16 h = __float2bfloat16(v[c]);
    o[c] = *reinterpret_cast<unsigned short*>(&h);
  }
  ((u16x4*)a.out[s])[j] = o;
}

// scale fp32 array by constant (cam_mask * log2e)
__global__ __launch_bounds__(256) void scale_f32_kernel(const float* __restrict__ in,
                                                        float* __restrict__ out,
                                                        float s, int n4) {
  int i = blockIdx.x * 256 + threadIdx.x;
  if (i < n4) {
    f4 v = ((const f4*)in)[i];
    ((f4*)out)[i] = v * s;
  }
}

// ------------------------------------------------------------------
// add fp32 + fp32 -> bf16
// ------------------------------------------------------------------
__global__ __launch_bounds__(256) void add_bf16_kernel(const float* __restrict__ a,
                                                       const float* __restrict__ b,
                                                       bf16* __restrict__ out, int n4) {
  int i = blockIdx.x * 256 + threadIdx.x;
  if (i < n4) {
    f4 x = ((const f4*)a)[i];
    f4 y = ((const f4*)b)[i];
    u16x4 o;
#pragma unroll
    for (int j = 0; j < 4; ++j) {
      bf16 h = __float2bfloat16(x[j] + y[j]);
      o[j] = *reinterpret_cast<unsigned short*>(&h);
    }
    ((u16x4*)out)[i] = o;
  }
}

// ------------------------------------------------------------------
// MFMA GEMM: C[M,N] = A[M,K] @ W[N,K]^T (+ bias[N])
// global_load_lds staging, linear LDS [TB][64] bf16, XOR-swizzled source
// columns + swizzled ds_read (involution: slot ^= row&7).
// MODE: 0 f32, 2 bf16+relu, 3 bf16 head layout (sec0 scaled by qscale),
//       4 f32 split-K partial,
//       5 bf16 transposed head layout (V^T) via LDS-transpose epilogue
//         (TB must be 64 for MODE 5)
// ------------------------------------------------------------------
template <int TB, int MODE, int SPLITK>
__global__ __launch_bounds__(256, 2) void mfma_gemm(
    const bf16* __restrict__ A, const bf16* __restrict__ W,
    const float* __restrict__ bias, float* __restrict__ C,
    bf16* __restrict__ Cb, int M, int N, int K, int HL, float qscale) {
  constexpr int WM = TB / 2, WN = TB / 2;
  constexpr int MR = WM / 16, NR = WN / 16;
  constexpr int NCH = TB / 32;
  __shared__ __attribute__((aligned(16))) unsigned short SH[TB * 128];
  unsigned short (*As)[64] = (unsigned short(*)[64])SH;
  unsigned short (*Ws)[64] = (unsigned short(*)[64])(SH + TB * 64);
  const int tid = threadIdx.x;
  const int lane = tid & 63, wave = tid >> 6;
  const int wr = wave >> 1, wc = wave & 1;
  const int bm = blockIdx.x * TB, bn = blockIdx.y * TB;
  const int fr = lane & 15, fo = lane >> 4;
  const int srowi = lane >> 3;
  const int slot = lane & 7;
  const int gcol = (slot ^ srowi) * 8;

  const int kchunk = K / SPLITK;
  const int kbeg = (SPLITK > 1) ? blockIdx.z * kchunk : 0;

  f32x4 acc[MR][NR] = {};

  for (int k0 = kbeg; k0 < kbeg + kchunk; k0 += 64) {
    __syncthreads();
#pragma unroll
    for (int c = 0; c < NCH; ++c) {
      int rbase = wave * (TB / 4) + c * 8;
      int row = rbase + srowi;
      async_cp16(A + (size_t)(bm + row) * K + k0 + gcol, &As[rbase][0]);
      async_cp16(W + (size_t)(bn + row) * K + k0 + gcol, &Ws[rbase][0]);
    }
    __syncthreads();
#pragma unroll
    for (int ks = 0; ks < 2; ++ks) {
      s8v a[MR], b[NR];
#pragma unroll
      for (int mi = 0; mi < MR; ++mi) {
        int row = wr * WM + mi * 16 + fr;
        a[mi] = *(const s8v*)((const char*)&As[0][0] + row * 128 +
                              ((ks * 64 + fo * 16) ^ ((row & 7) << 4)));
      }
#pragma unroll
      for (int ni = 0; ni < NR; ++ni) {
        int row = wc * WN + ni * 16 + fr;
        b[ni] = *(const s8v*)((const char*)&Ws[0][0] + row * 128 +
                              ((ks * 64 + fo * 16) ^ ((row & 7) << 4)));
      }
#pragma unroll
      for (int mi = 0; mi < MR; ++mi)
#pragma unroll
        for (int ni = 0; ni < NR; ++ni)
          acc[mi][ni] = __builtin_amdgcn_mfma_f32_16x16x32_bf16(
              a[mi], b[ni], acc[mi][ni], 0, 0, 0);
    }
  }

  const int r0 = (lane >> 4) * 4;

  if (MODE == 5) {
    // LDS-transpose epilogue: T[col][row] (64x72 u16), then 16B chunk stores
    __syncthreads();
    unsigned short (*T)[72] = (unsigned short(*)[72])SH;
#pragma unroll
    for (int mi = 0; mi < MR; ++mi)
#pragma unroll
      for (int ni = 0; ni < NR; ++ni) {
        int colL = wc * WN + ni * 16 + fr;
        float bv = bias[bn + colL];
#pragma unroll
        for (int r = 0; r < 4; ++r) {
          int rowL = wr * WM + mi * 16 + r0 + r;
          bf16 hv = __float2bfloat16(acc[mi][ni][r] + bv);
          T[colL][rowL] = *(unsigned short*)&hv;
        }
      }
    __syncthreads();
    const int lbase = bm >> 3;
#pragma unroll
    for (int jj = 0; jj < 2; ++jj) {
      int cid = tid * 2 + jj;
      int colL = cid >> 3, bb = cid & 7;
      int c = bn + colL;
      int sec = c >> 8, hh = (c >> 5) & 7, d = c & 31;
      u16x8 v;
#pragma unroll
      for (int l = 0; l < 8; ++l) v[l] = T[colL][bb + 8 * l];
      *(u16x8*)(Cb + (size_t)sec * ((size_t)64 * 32 * HL) +
                ((size_t)(bb * 8 + hh) * 32 + d) * HL + lbase) = v;
    }
    return;
  }

  float* Cz = (MODE == 4) ? C + (size_t)blockIdx.z * M * N : C;
#pragma unroll
  for (int mi = 0; mi < MR; ++mi) {
#pragma unroll
    for (int ni = 0; ni < NR; ++ni) {
      int col = bn + wc * WN + ni * 16 + fr;
      float bv = (MODE == 4) ? 0.f : bias[col];
#pragma unroll
      for (int r = 0; r < 4; ++r) {
        int row = bm + wr * WM + mi * 16 + r0 + r;
        float t = acc[mi][ni][r] + bv;
        if (MODE == 2) t = fmaxf(t, 0.f);
        if (MODE == 0) {
          C[(size_t)row * N + col] = t;
        } else if (MODE == 4) {
          Cz[(size_t)row * N + col] = t;
        } else if (MODE == 3) {
          int l = row >> 3, bb = row & 7;
          int sec = col >> 8, hh = (col >> 5) & 7, d = col & 31;
          if (sec == 0) t *= qscale;
          Cb[(size_t)sec * ((size_t)64 * HL * 32) +
             ((size_t)(bb * 8 + hh) * HL + l) * 32 + d] = __float2bfloat16(t);
        } else {
          Cb[(size_t)row * N + col] = __float2bfloat16(t);
        }
      }
    }
  }
}

// ------------------------------------------------------------------
// Swapped-operand MFMA flash attention (in-lane softmax, no barriers).
// Qh: (64, L, 32) bf16, pre-scaled by (1/sqrt(32))*log2e.
// Kh: (64, S, 32) bf16. VhT: (64, 32, S) bf16 (transposed head layout).
// bias (optional): (8, L, S) fp32, pre-scaled by log2e.
// NW waves/block, 16 q-rows per wave.
// grid (64 bh, ceil(L/(NW*16)), nz). block NW*64.
// ------------------------------------------------------------------
template <int HAS_BIAS, int PARTIAL, int NW>
__global__ __launch_bounds__(NW * 64, 4) void attn_mfma(
    const bf16* __restrict__ Qh, const bf16* __restrict__ Kh,
    const bf16* __restrict__ VhT, const float* __restrict__ bias,
    bf16* __restrict__ O, float* __restrict__ PO, float* __restrict__ PM,
    float* __restrict__ PL, int L, int S, int SC) {
  __shared__ __attribute__((aligned(16))) uint32_t Ps2[NW][16][36];
  const int tid = threadIdx.x;
  const int lane = tid & 63, wave = tid >> 6;
  const int fr = lane & 15, fo = lane >> 4;
  const int bh = blockIdx.x;
  const int b = bh >> 3, h = bh & 7;
  const int q0 = blockIdx.y * (NW * 16) + wave * 16;
  const int q = q0 + fr;

  const int cz = PARTIAL ? blockIdx.z : 0;
  const int sb = PARTIAL ? cz * SC : 0;
  const int se = PARTIAL ? min(S, sb + SC) : S;

  s8v qf = {};
  if (q < L) qf = *(const s8v*)(Qh + ((size_t)bh * L + q) * 32 + fo * 8);

  const float* brow = nullptr;
  if (HAS_BIAS) brow = bias + ((size_t)b * L + (q < L ? q : L - 1)) * S;

  float m = -1e30f, lsum = 0.f;
  f32x4 oacc[2] = {};

  // K fragment loader: kf[kb] = K[key = s0 + kb*16 + fr][d = fo*8..+7]
  s8v kf[4];
#pragma unroll
  for (int kb = 0; kb < 4; ++kb)
    kf[kb] = *(const s8v*)(Kh + ((size_t)bh * S + sb + kb * 16 + fr) * 32 + fo * 8);

  for (int s0 = sb; s0 < se; s0 += 64) {
    const bool more = (s0 + 64 < se);
    s8v kn[4];
    if (more) {
#pragma unroll
      for (int kb = 0; kb < 4; ++kb)
        kn[kb] = *(const s8v*)(Kh + ((size_t)bh * S + s0 + 64 + kb * 16 + fr) * 32 + fo * 8);
    }
    // V^T fragments: vf[dh][ks] = V^T[d = dh*16 + fr][key = s0 + ks*32 + fo*8..+7]
    s8v vf[2][2];
#pragma unroll
    for (int dh = 0; dh < 2; ++dh)
#pragma unroll
      for (int ks = 0; ks < 2; ++ks)
        vf[dh][ks] = *(const s8v*)(VhT + ((size_t)bh * 32 + dh * 16 + fr) * S +
                                   s0 + ks * 32 + fo * 8);
    f4 bias4[4];
    if (HAS_BIAS) {
#pragma unroll
      for (int kb = 0; kb < 4; ++kb)
        bias4[kb] = *(const f4*)(brow + s0 + kb * 16 + 4 * fo);
    }

    // QK^T swapped: sa[kb] = S^T[key-block][q]; col=q=fr, row=4*fo+r
    f32x4 sa[4];
#pragma unroll
    for (int kb = 0; kb < 4; ++kb) {
      f32x4 z = {};
      sa[kb] = __builtin_amdgcn_mfma_f32_16x16x32_bf16(kf[kb], qf, z, 0, 0, 0);
    }

    float lg[16];
#pragma unroll
    for (int kb = 0; kb < 4; ++kb)
#pragma unroll
      for (int r = 0; r < 4; ++r)
        lg[kb * 4 + r] = HAS_BIAS ? sa[kb][r] + bias4[kb][r] : sa[kb][r];

    if (s0 + 64 > se) {  // boundary tile: mask invalid keys
#pragma unroll
      for (int kb = 0; kb < 4; ++kb)
#pragma unroll
        for (int r = 0; r < 4; ++r)
          if (s0 + kb * 16 + 4 * fo + r >= se) lg[kb * 4 + r] = -1e30f;
    }

    // tile max: in-lane tree (v_max3-friendly) + 2 cross-fo shuffles
    float t0 = fmaxf(fmaxf(lg[0], lg[1]), fmaxf(lg[2], lg[3]));
    float t1 = fmaxf(fmaxf(lg[4], lg[5]), fmaxf(lg[6], lg[7]));
    float t2 = fmaxf(fmaxf(lg[8], lg[9]), fmaxf(lg[10], lg[11]));
    float t3 = fmaxf(fmaxf(lg[12], lg[13]), fmaxf(lg[14], lg[15]));
    float tm = fmaxf(fmaxf(t0, t1), fmaxf(t2, t3));
    tm = fmaxf(tm, __shfl_xor(tm, 16));
    tm = fmaxf(tm, __shfl_xor(tm, 32));

    // deferred rescale (wave-uniform)
    if (__any(tm > m + 8.f)) {
      float nm = fmaxf(m, tm);
      float rs = EXP2(m - nm);
      m = nm;
      lsum *= rs;
#pragma unroll
      for (int r = 0; r < 4; ++r) { oacc[0][r] *= rs; oacc[1][r] *= rs; }
    }

    float pr[16];
    float ps = 0.f;
#pragma unroll
    for (int i = 0; i < 16; ++i) {
      pr[i] = EXP2(lg[i] - m);
      ps += pr[i];
    }
    lsum += ps;  // partial (this lane's 16 keys); cross-fo reduced at end

    // pack P -> per-wave LDS: row=q(fr), u32 idx = key/2
#pragma unroll
    for (int kb = 0; kb < 4; ++kb) {
      uint32_t w0 = pkbf(pr[kb * 4 + 0], pr[kb * 4 + 1]);
      uint32_t w1 = pkbf(pr[kb * 4 + 2], pr[kb * 4 + 3]);
      uint64_t w = (uint64_t)w0 | ((uint64_t)w1 << 32);
      *(uint64_t*)&Ps2[wave][fr][kb * 8 + 2 * fo] = w;
    }

    // P^T fragments: pf[ks] lane holds P[q=fr][key = ks*32 + fo*8..+7]
    s8v pf[2];
#pragma unroll
    for (int ks = 0; ks < 2; ++ks)
      pf[ks] = *(const s8v*)&Ps2[wave][fr][ks * 16 + 4 * fo];

    // PV swapped: oacc[dh] = O^T[d][q], col=q=fr, row d = dh*16 + 4*fo + r
#pragma unroll
    for (int dh = 0; dh < 2; ++dh)
#pragma unroll
      for (int ks = 0; ks < 2; ++ks)
        oacc[dh] = __builtin_amdgcn_mfma_f32_16x16x32_bf16(
            vf[dh][ks], pf[ks], oacc[dh], 0, 0, 0);

    if (more) {
#pragma unroll
      for (int kb = 0; kb < 4; ++kb) kf[kb] = kn[kb];
    }
  }

  // full row-sum across the 4 fo-lanes
  lsum += __shfl_xor(lsum, 16);
  lsum += __shfl_xor(lsum, 32);

  if (q < L) {
    if (PARTIAL) {
      size_t pi = ((size_t)cz * 64 + bh) * L + q;
      float* po = PO + pi * 32;
#pragma unroll
      for (int dh = 0; dh < 2; ++dh) {
        f4 t;
#pragma unroll
        for (int r = 0; r < 4; ++r) t[r] = oacc[dh][r];
        *(f4*)(po + dh * 16 + 4 * fo) = t;
      }
      if (fo == 0) { PM[pi] = m; PL[pi] = lsum; }
    } else {
      float inv = 1.f / lsum;
      bf16* op = O + ((size_t)q * 8 + b) * 256 + h * 32;
#pragma unroll
      for (int dh = 0; dh < 2; ++dh) {
        uint32_t w0 = pkbf(oacc[dh][0] * inv, oacc[dh][1] * inv);
        uint32_t w1 = pkbf(oacc[dh][2] * inv, oacc[dh][3] * inv);
        *(uint32_t*)(op + dh * 16 + 4 * fo) = w0;
        *(uint32_t*)(op + dh * 16 + 4 * fo + 2) = w1;
      }
    }
  }
}

// ------------------------------------------------------------------
// combine NC S-chunk partials -> O bf16 (thread per (bh,q,d))
// NOTE: PM/PL are in log2 domain (exp2 weights).
// ------------------------------------------------------------------
__global__ __launch_bounds__(256) void attn_combine(
    const float* __restrict__ PO, const float* __restrict__ PM,
    const float* __restrict__ PL, bf16* __restrict__ O, int L, int NC) {
  int gid = blockIdx.x * 256 + threadIdx.x;
  if (gid >= 64 * L * 32) return;
  int d = gid & 31;
  int rem = gid >> 5;
  int q = rem % L, bh = rem / L;
  int b = bh >> 3, h = bh & 7;
  float M = -1e30f;
  for (int c = 0; c < NC; ++c) M = fmaxf(M, PM[((size_t)c * 64 + bh) * L + q]);
  float lsum = 0.f, o = 0.f;
  for (int c = 0; c < NC; ++c) {
    size_t pi = ((size_t)c * 64 + bh) * L + q;
    float w = EXP2(PM[pi] - M);
    lsum += PL[pi] * w;
    o += PO[pi * 32 + d] * w;
  }
  O[((size_t)q * 8 + b) * 256 + h * 32 + d] = __float2bfloat16(o / lsum);
}

// ------------------------------------------------------------------
// LayerNorm over last dim (256): v = x (+res) (+Σ parts) (+gbias);
// out = LN(v)*g + b ; dual output (f32 + bf16)
// ------------------------------------------------------------------
__global__ __launch_bounds__(256) void ln_kernel(
    const float* __restrict__ x, const float* __restrict__ res,
    const float* __restrict__ parts, int nparts, int pstride,
    const float* __restrict__ gbias,
    const float* __restrict__ g, const float* __restrict__ b,
    float* __restrict__ out, bf16* __restrict__ outb) {
  const int row = blockIdx.x, tid = threadIdx.x;
  size_t idx = (size_t)row * 256 + tid;
  float v = x[idx];
  if (res) v += res[idx];
  if (parts) {
    for (int z = 0; z < nparts; ++z) v += parts[(size_t)z * pstride + idx];
  }
  if (gbias) v += gbias[tid];
  float s = v, s2 = v * v;
#pragma unroll
  for (int off = 32; off >= 1; off >>= 1) {
    s += __shfl_down(s, off);
    s2 += __shfl_down(s2, off);
  }
  __shared__ float red[8];
  int wv = tid >> 6;
  if ((tid & 63) == 0) { red[wv] = s; red[4 + wv] = s2; }
  __syncthreads();
  if (tid == 0) {
    float ts = red[0] + red[1] + red[2] + red[3];
    float ts2 = red[4] + red[5] + red[6] + red[7];
    float mu = ts * (1.f / 256.f);
    float var = ts2 * (1.f / 256.f) - mu * mu;
    red[0] = mu;
    red[1] = rsqrtf(var + LN_EPS);
  }
  __syncthreads();
  float y = (v - red[0]) * red[1] * g[tid] + b[tid];
  if (out) out[idx] = y;
  if (outb) outb[idx] = __float2bfloat16(y);
}

// ------------------------------------------------------------------
// Host orchestration
// ------------------------------------------------------------------
extern "C" void kernel_launch(void* const* d_in, const int* in_sizes, int n_in,
                              void* d_out, int out_size, void* d_ws, size_t ws_size,
                              hipStream_t stream) {
  const float* src         = (const float*)d_in[0];
  const float* pos         = (const float*)d_in[1];
  const float* query_embed = (const float*)d_in[2];
  const float* cam_mask    = (const float*)d_in[3];
  const float* enc_qkv_w   = (const float*)d_in[4];
  const float* enc_qkv_b   = (const float*)d_in[5];
  const float* enc_out_w   = (const float*)d_in[6];
  const float* enc_out_b   = (const float*)d_in[7];
  const float* enc_ln1_g   = (const float*)d_in[8];
  const float* enc_ln1_b   = (const float*)d_in[9];
  const float* enc_ff1_w   = (const float*)d_in[10];
  const float* enc_ff1_b   = (const float*)d_in[11];
  const float* enc_ff2_w   = (const float*)d_in[12];
  const float* enc_ff2_b   = (const float*)d_in[13];
  const float* enc_ln2_g   = (const float*)d_in[14];
  const float* enc_ln2_b   = (const float*)d_in[15];
  const float* dec_sa_qkv_w= (const float*)d_in[16];
  const float* dec_sa_qkv_b= (const float*)d_in[17];
  const float* dec_sa_out_w= (const float*)d_in[18];
  const float* dec_sa_out_b= (const float*)d_in[19];
  const float* dec_ln1_g   = (const float*)d_in[20];
  const float* dec_ln1_b   = (const float*)d_in[21];
  const float* dec_ca_qkv_w= (const float*)d_in[22];
  const float* dec_ca_qkv_b= (const float*)d_in[23];
  const float* dec_ca_out_w= (const float*)d_in[24];
  const float* dec_ca_out_b= (const float*)d_in[25];
  const float* dec_ln2_g   = (const float*)d_in[26];
  const float* dec_ln2_b   = (const float*)d_in[27];
  const float* dec_ff1_w   = (const float*)d_in[28];
  const float* dec_ff1_b   = (const float*)d_in[29];
  const float* dec_ff2_w   = (const float*)d_in[30];
  const float* dec_ff2_b   = (const float*)d_in[31];
  const float* dec_ln3_g   = (const float*)d_in[32];
  const float* dec_ln3_b   = (const float*)d_in[33];
  const float* dec_norm_g  = (const float*)d_in[34];
  const float* dec_norm_b  = (const float*)d_in[35];

  // ---------------- workspace layout ----------------
  size_t off = 0;
  char* base = (char*)d_ws;
  auto af = [&](size_t n) { float* p = (float*)(base + off); off += n * 4; return p; };
  auto ab = [&](size_t n) { bf16*  p = (bf16*)(base + off);  off += n * 2; return p; };

  float* mem  = af(2097152);
  float* r1   = af(2097152);
  float* PO   = af(8388608);   // split-K / attn partials
  float* pm   = af(262144);
  float* pl   = af(262144);
  float* cmlog= af(655360);    // cam_mask * log2e
  float* pb   = af(1024);      // packed CA K/V biases
  float* tgt  = af(163840);
  float* tpr  = af(163840);
  bf16* memb  = ab(2097152);
  bf16* qkb   = ab(2097152);
  bf16* aob   = ab(2097152);
  bf16* ffb   = ab(16777216);
  bf16* bufQ  = ab(4194304);   // Q section + batched-K section
  bf16* bufK  = ab(4194304);   // CA K, both layers
  bf16* bufV  = ab(4194304);   // CA V^T, both layers (enc V^T uses [0..2M))
  bf16* bufVsa= ab(163840);    // SA V^T per layer
  bf16* tgtb  = ab(163840);
  bf16* tqkb  = ab(163840);
  bf16* taob  = ab(163840);
  bf16* tffb  = ab(1310720);
  bf16* w_enc_qkv = ab(393216);
  bf16* w_enc_out = ab(131072);
  bf16* w_enc_ff1 = ab(1048576);
  bf16* w_enc_ff2 = ab(1048576);
  bf16* w_sa_qkv  = ab(393216);
  bf16* w_sa_out  = ab(131072);
  bf16* w_ca_q    = ab(131072);   // [Q0;Q1]
  bf16* w_ca_kv   = ab(262144);   // [K0;K1;V0;V1]
  bf16* w_ca_out  = ab(131072);
  bf16* w_dec_ff1 = ab(1048576);
  bf16* w_dec_ff2 = ab(1048576);

  // (1/sqrt(32)) * log2(e) folded into Q projection
  const float qscale = 0.17677669529663687f * LOG2E;

  // ---- fused weight + src casts (CA qkv re-packed per-section) ----
  {
    CastArgs ca;
    const float* ins[NCAST] = {
        enc_qkv_w, enc_out_w, enc_ff1_w, enc_ff2_w,
        dec_sa_qkv_w, dec_sa_out_w,
        dec_ca_qkv_w,            // Q0
        dec_ca_qkv_w + 65536,    // K0
        dec_ca_qkv_w + 131072,   // V0
        dec_ca_qkv_w + 196608,   // Q1
        dec_ca_qkv_w + 262144,   // K1
        dec_ca_qkv_w + 327680,   // V1
        dec_ca_out_w, dec_ff1_w, dec_ff2_w, src};
    bf16* outs[NCAST] = {
        w_enc_qkv, w_enc_out, w_enc_ff1, w_enc_ff2,
        w_sa_qkv, w_sa_out,
        w_ca_q,              // Q0
        w_ca_kv,             // K0
        w_ca_kv + 131072,    // V0
        w_ca_q + 65536,      // Q1
        w_ca_kv + 65536,     // K1
        w_ca_kv + 196608,    // V1
        w_ca_out, w_dec_ff1, w_dec_ff2, memb};
    int n4s[NCAST] = {98304, 32768, 262144, 262144, 98304, 32768,
                      16384, 16384, 16384, 16384, 16384, 16384,
                      32768, 262144, 262144, 524288};
    int acc = 0;
    for (int s = 0; s < NCAST; ++s) {
      ca.in[s] = ins[s]; ca.out[s] = outs[s];
      acc += n4s[s]; ca.end4[s] = acc;
    }
    ca.nseg = NCAST;
    cast_multi<<<(acc + 255) / 256, 256, 0, stream>>>(ca, acc);
  }
  scale_f32_kernel<<<640, 256, 0, stream>>>(cam_mask, cmlog, LOG2E, 163840);
  hipMemcpyAsync(mem, src, (size_t)2097152 * 4, hipMemcpyDeviceToDevice, stream);
  // packed CA biases: [K0b;K1b;V0b;V1b]
  hipMemcpyAsync(pb,       dec_ca_qkv_b + 256,       1024, hipMemcpyDeviceToDevice, stream);
  hipMemcpyAsync(pb + 256, dec_ca_qkv_b + 768 + 256, 1024, hipMemcpyDeviceToDevice, stream);
  hipMemcpyAsync(pb + 512, dec_ca_qkv_b + 512,       1024, hipMemcpyDeviceToDevice, stream);
  hipMemcpyAsync(pb + 768, dec_ca_qkv_b + 768 + 512, 1024, hipMemcpyDeviceToDevice, stream);

  // GEMM launch helpers
  auto g64_f = [&](const bf16* A, const bf16* W, const float* bias, float* C,
                   int M, int N, int K) {
    mfma_gemm<64, 0, 1><<<dim3(M / 64, N / 64), 256, 0, stream>>>(
        A, W, bias, C, nullptr, M, N, K, 0, 1.f);
  };
  auto g64_head = [&](const bf16* A, const bf16* W, const float* bias, bf16* Cb,
                      int M, int N, int K, int HL, float qs) {
    mfma_gemm<64, 3, 1><<<dim3(M / 64, N / 64), 256, 0, stream>>>(
        A, W, bias, nullptr, Cb, M, N, K, HL, qs);
  };
  auto g64_headT = [&](const bf16* A, const bf16* W, const float* bias, bf16* Cb,
                       int M, int N, int K, int HL) {
    mfma_gemm<64, 5, 1><<<dim3(M / 64, N / 64), 256, 0, stream>>>(
        A, W, bias, nullptr, Cb, M, N, K, HL, 1.f);
  };
  auto g64_relu = [&](const bf16* A, const bf16* W, const float* bias, bf16* Cb,
                      int M, int N, int K) {
    mfma_gemm<64, 2, 1><<<dim3(M / 64, N / 64), 256, 0, stream>>>(
        A, W, bias, nullptr, Cb, M, N, K, 0, 1.f);
  };
  auto g128_relu = [&](const bf16* A, const bf16* W, const float* bias, bf16* Cb,
                       int M, int N, int K) {
    mfma_gemm<128, 2, 1><<<dim3(M / 128, N / 128), 256, 0, stream>>>(
        A, W, bias, nullptr, Cb, M, N, K, 0, 1.f);
  };

  // ---------------- encoder ----------------
  for (int i = 0; i < 2; ++i) {
    const bf16* wq = w_enc_qkv + (size_t)i * 196608;
    const float* qkvb = enc_qkv_b + (size_t)i * 768;
    add_bf16_kernel<<<2048, 256, 0, stream>>>(mem, pos, qkb, 524288);
    g64_head(qkb, wq, qkvb, bufQ, 8192, 512, 256, 1024, qscale);           // Q + K
    g64_headT(memb, wq + 131072, qkvb + 512, bufV, 8192, 256, 256, 1024);  // V^T
    attn_mfma<0, 0, 4><<<dim3(64, 16), 256, 0, stream>>>(
        bufQ, bufQ + 2097152, bufV, nullptr, aob, nullptr, nullptr, nullptr,
        1024, 1024, 0);
    g64_f(aob, w_enc_out + (size_t)i * 65536, enc_out_b + i * 256, r1,
          8192, 256, 256);
    ln_kernel<<<8192, 256, 0, stream>>>(mem, r1, nullptr, 0, 0, nullptr,
                                        enc_ln1_g + i * 256, enc_ln1_b + i * 256,
                                        mem, memb);
    g128_relu(memb, w_enc_ff1 + (size_t)i * 524288, enc_ff1_b + i * 2048, ffb,
              8192, 2048, 256);
    mfma_gemm<128, 4, 4><<<dim3(64, 2, 4), 256, 0, stream>>>(
        ffb, w_enc_ff2 + (size_t)i * 524288, nullptr, PO, nullptr,
        8192, 256, 2048, 0, 1.f);
    ln_kernel<<<8192, 256, 0, stream>>>(mem, nullptr, PO, 4, 2097152,
                                        enc_ff2_b + i * 256,
                                        enc_ln2_g + i * 256, enc_ln2_b + i * 256,
                                        mem, memb);
  }

  // ---------------- decoder ----------------
  hipMemsetAsync(tgt, 0, (size_t)163840 * 4, stream);
  hipMemsetAsync(tgtb, 0, (size_t)163840 * 2, stream);
  add_bf16_kernel<<<2048, 256, 0, stream>>>(mem, pos, qkb, 524288);  // CA key input

  // Hoisted CA K/V projections (both layers, batched N=512)
  g64_head(qkb, w_ca_kv, pb, bufK, 8192, 512, 256, 1024, 1.f);             // K0|K1
  g64_headT(memb, w_ca_kv + 131072, pb + 512, bufV, 8192, 512, 256, 1024); // V0|V1

  for (int i = 0; i < 2; ++i) {
    const bf16* wsa = w_sa_qkv + (size_t)i * 196608;
    const float* sab = dec_sa_qkv_b + (size_t)i * 768;
    const float* cab = dec_ca_qkv_b + (size_t)i * 768;

    // self-attention
    add_bf16_kernel<<<160, 256, 0, stream>>>(tgt, query_embed, tqkb, 40960);
    g64_head(tqkb, wsa, sab, bufQ, 640, 512, 256, 80, qscale);             // Q + K
    g64_headT(tgtb, wsa + 131072, sab + 512, bufVsa, 640, 256, 256, 80);   // V^T
    attn_mfma<0, 0, 1><<<dim3(64, 5), 64, 0, stream>>>(
        bufQ, bufQ + 163840, bufVsa, nullptr, taob, nullptr, nullptr, nullptr,
        80, 80, 0);
    g64_f(taob, w_sa_out + (size_t)i * 65536, dec_sa_out_b + i * 256, tpr,
          640, 256, 256);
    ln_kernel<<<640, 256, 0, stream>>>(tgt, tpr, nullptr, 0, 0, nullptr,
                                       dec_ln1_g + i * 256, dec_ln1_b + i * 256,
                                       tgt, tgtb);
    // cross-attention (S split into 8 chunks of 128 + combine)
    add_bf16_kernel<<<160, 256, 0, stream>>>(tgt, query_embed, tqkb, 40960);
    g64_head(tqkb, w_ca_q + (size_t)i * 65536, cab, bufQ, 640, 256, 256, 80, qscale);
    attn_mfma<1, 1, 1><<<dim3(64, 5, 8), 64, 0, stream>>>(
        bufQ, bufK + (size_t)i * 2097152, bufV + (size_t)i * 2097152, cmlog,
        nullptr, PO, pm, pl, 80, 1024, 128);
    attn_combine<<<640, 256, 0, stream>>>(PO, pm, pl, taob, 80, 8);
    g64_f(taob, w_ca_out + (size_t)i * 65536, dec_ca_out_b + i * 256, tpr,
          640, 256, 256);
    ln_kernel<<<640, 256, 0, stream>>>(tgt, tpr, nullptr, 0, 0, nullptr,
                                       dec_ln2_g + i * 256, dec_ln2_b + i * 256,
                                       tgt, tgtb);
    // feed-forward
    g64_relu(tgtb, w_dec_ff1 + (size_t)i * 524288, dec_ff1_b + i * 2048, tffb,
             640, 2048, 256);
    mfma_gemm<64, 4, 4><<<dim3(10, 4, 4), 256, 0, stream>>>(
        tffb, w_dec_ff2 + (size_t)i * 524288, nullptr, PO, nullptr,
        640, 256, 2048, 0, 1.f);
    ln_kernel<<<640, 256, 0, stream>>>(tgt, nullptr, PO, 4, 163840,
                                       dec_ff2_b + i * 256,
                                       dec_ln3_g + i * 256, dec_ln3_b + i * 256,
                                       tgt, tgtb);
  }

  // final norm -> fp32 output
  ln_kernel<<<640, 256, 0, stream>>>(tgt, nullptr, nullptr, 0, 0, nullptr,
                                     dec_norm_g, dec_norm_b,
                                     (float*)d_out, nullptr);
}